// Round 8
// baseline (417.526 us; speedup 1.0000x reference)
//
#include <hip/hip_runtime.h>
#include <math.h>

// Problem constants
#define S_LEN   2048
#define E_DIM   2048
#define NH      64
#define P_DIM   64
#define N_DIM   128
#define CS      256
#define NCHUNK  8
#define INTER   4096
#define CONVD   4352
#define PROJ    8512
#define GEMM1N  8448       // INTER + CONVD = 66*128 = 33*256 exactly
#define EPS     1e-5f

// Workspace layout (float units)
#define OFF_PROJBF 0ull                        // bf16 2048*8448 = 8,650,752 fl
#define OFF_HBC    8650752ull                  // bf16 2048*4352 = 4,456,448 fl
#define OFF_DTG    13107200ull                 // fp32 2048*64   =   131,072 fl
#define OFF_DTPART 13238272ull                 // fp32 32*2048*64 = 4,194,304 fl
#define OFF_GM     17432576ull                 // fp32 8*256*256 =   524,288 fl
#define OFF_YV     17956864ull                 // fp32 2048*4096 = 8,388,608 fl
#define OFF_R      26345472ull                 // Xbf(2,097,152 fl) + Winbf(8,650,752 fl)
#define OFF_WOUT   37093376ull                 // bf16 2048*4096 = 2,097,152 fl
// ws end = 39,190,528 fl = 156.8 MB.
// ynbf aliases Xbf (R+0) — written by norm, after GEMM1's last read of Xbf.
// GEMM2 split-K=4 partials: 4 x 4,194,304 fl FP32 at ws[0 .. 16,777,216) —
// the projbf/hbc/dtg/dtpart regions, all dead before GEMM2 launches.
// (bf16 partials measured R7: +5-9us REGRESSION — 16 cols x 2B = 32B
// partial-line stores -> L2 RMW; fp32 = 64B full lines.)

typedef __bf16 bf16x8 __attribute__((ext_vector_type(8)));
typedef float  f32x4  __attribute__((ext_vector_type(4)));
typedef float  f32x16 __attribute__((ext_vector_type(16)));

__device__ __forceinline__ float bf2f(unsigned short u) {
    union { unsigned int i; float f; } v; v.i = ((unsigned int)u) << 16; return v.f;
}
__device__ __forceinline__ unsigned short f2bf(float f) {
    union { float f; unsigned int i; } v; v.f = f;
    unsigned int r = v.i + 0x7FFFu + ((v.i >> 16) & 1u);
    return (unsigned short)(r >> 16);
}
__device__ __forceinline__ void gl_lds16(const void* g, void* l) {
    __builtin_amdgcn_global_load_lds(
        (const __attribute__((address_space(1))) void*)g,
        (__attribute__((address_space(3))) void*)l, 16, 0, 0);
}

// ---------------------------------------------------------------------------
// merged fp32 -> bf16 cast of X / W_in[0:8448] / W_out (one launch)
// ---------------------------------------------------------------------------
__global__ __launch_bounds__(256) void cast3_kernel(
    const float* __restrict__ X, const float* __restrict__ Win,
    const float* __restrict__ Wout, unsigned short* __restrict__ Xbf,
    unsigned short* __restrict__ Winbf, unsigned short* __restrict__ Woutbf)
{
    const int blk = blockIdx.x;
    const float* src; unsigned short* dst; size_t off;
    if (blk < 2048)       { src = X;    dst = Xbf;    off = (size_t)blk * 2048; }
    else if (blk < 10496) { src = Win;  dst = Winbf;  off = (size_t)(blk - 2048) * 2048; }
    else                  { src = Wout; dst = Woutbf; off = (size_t)(blk - 10496) * 2048; }
    size_t i = off + (size_t)threadIdx.x * 8;
    float4 a = *(const float4*)(src + i);
    float4 b = *(const float4*)(src + i + 4);
    uint4 o;
    o.x = (unsigned int)f2bf(a.x) | ((unsigned int)f2bf(a.y) << 16);
    o.y = (unsigned int)f2bf(a.z) | ((unsigned int)f2bf(a.w) << 16);
    o.z = (unsigned int)f2bf(b.x) | ((unsigned int)f2bf(b.y) << 16);
    o.w = (unsigned int)f2bf(b.z) | ((unsigned int)f2bf(b.w) << 16);
    *(uint4*)(dst + i) = o;
}

// ---------------------------------------------------------------------------
// 256x256 8-phase bf16 NT GEMM (HK-style schedule, plain HIP).
// Used ONLY where the grid is exactly <=256 blocks (GEMM2: 8x8x4).
// RACE-FIXED gates (R5/R6, tripwire-verified): vmcnt is PER-WAVE; a
// half-tile is staged by all 8 waves cooperatively, so every gate is
// wait -> BARRIER -> read:
//   end-p1: WAITV(8)  drains A1(tt)            (read at p2)
//   end-p3: WAITV(6)  drains A0(tt+1),B0(tt+1) (read at next p0)
//   tail: WAITV(0) / WAITV(2) by the same per-wave queue arithmetic.
// C[m][n] = sum_k A[m][k]*B[n][k].  BK=64, 512 threads = 8 waves (2M x 4N).
//   quadrants: p0 (0,0)  p1 (0,1)  p2 (1,1)  p3 (1,0)
//   stages:    p0 B0(t+1) p1 A1(t+1) p2 A0(t+2) p3 B1(t+2)
// Cb (bf16 out) and Cf (fp32 out) both honor the blockIdx.z * sC offset.
// M%256==0, N%256==0, K%64==0, K/64 >= 2.
// ---------------------------------------------------------------------------
#define WAITV(n) asm volatile("s_waitcnt vmcnt(" #n ")" ::: "memory")
#define BARR()   asm volatile("s_barrier" ::: "memory")

__global__ __launch_bounds__(512, 2) void gemm256_8ph(
    const unsigned short* __restrict__ A, int lda, long long sA,
    const unsigned short* __restrict__ B, int ldb, long long sB,
    float* __restrict__ Cf, unsigned short* __restrict__ Cb, int ldc,
    long long sC, int K, int mswap)
{
    __shared__ unsigned short sm[65536];   // 128 KB, [buf][A/B][half][128][64]
    A += (long long)blockIdx.z * sA;
    B += (long long)blockIdx.z * sB;
    const int t    = threadIdx.x;
    const int m0   = (mswap ? blockIdx.x : blockIdx.y) * 256;
    const int n0   = (mswap ? blockIdx.y : blockIdx.x) * 256;
    const int lane = t & 63;
    const int w    = t >> 6;
    const int wm   = ((w >> 2) & 1) * 64;   // row base within each A-half
    const int wn   = (w & 3) * 32;          // col base within each B-half
    const int l15  = lane & 15;
    const int l4   = lane >> 4;
    const int NT   = K >> 6;

    // staging: load j covers row (t>>3)+64j of the half, 16B chunk (t&7)^swz(r)
    const int sr = t >> 3, sl = t & 7;

    auto STAGE = [&](int T, int h, int isB) {
        const unsigned short* G = isB ? B : A;
        const int ld   = isB ? ldb : lda;
        const int base = (isB ? n0 : m0) + h * 128;
        unsigned short* dst =
            &sm[(T & 1) * 32768 + isB * 16384 + h * 8192 + t * 8];
#pragma unroll
        for (int j = 0; j < 2; j++) {
            const int r   = sr + 64 * j;
            const int gch = sl ^ ((r ^ (r >> 3)) & 7);
            gl_lds16(G + (size_t)(base + r) * ld + T * 64 + gch * 8,
                     dst + j * 4096);
        }
    };

    // fragment LDS offsets (rows within half)
    int aoff[4], asw[4], boff[2], bsw[2];
#pragma unroll
    for (int mi = 0; mi < 4; mi++) {
        int r = wm + mi * 16 + l15;
        aoff[mi] = r * 64; asw[mi] = (r ^ (r >> 3)) & 7;
    }
#pragma unroll
    for (int ni = 0; ni < 2; ni++) {
        int r = wn + ni * 16 + l15;
        boff[ni] = r * 64; bsw[ni] = (r ^ (r >> 3)) & 7;
    }

    bf16x8 aF[4][2], bF[2][2][2];
    f32x4  acc[2][2][4][2];
#pragma unroll
    for (int qm = 0; qm < 2; qm++)
#pragma unroll
        for (int qn = 0; qn < 2; qn++)
#pragma unroll
            for (int mi = 0; mi < 4; mi++)
#pragma unroll
                for (int ni = 0; ni < 2; ni++)
                    acc[qm][qn][mi][ni] = (f32x4){0.f, 0.f, 0.f, 0.f};

#define LOAD_A(qm) do { \
    const unsigned short* p_ = &sm[cb + (qm) * 8192]; \
    _Pragma("unroll") for (int mi = 0; mi < 4; mi++) \
    _Pragma("unroll") for (int ks = 0; ks < 2; ks++) \
        aF[mi][ks] = *(const bf16x8*)&p_[aoff[mi] + \
            (((ks * 4 + l4) ^ asw[mi]) << 3)]; \
} while (0)
#define LOAD_B(qn) do { \
    const unsigned short* p_ = &sm[cb + 16384 + (qn) * 8192]; \
    _Pragma("unroll") for (int ni = 0; ni < 2; ni++) \
    _Pragma("unroll") for (int ks = 0; ks < 2; ks++) \
        bF[qn][ni][ks] = *(const bf16x8*)&p_[boff[ni] + \
            (((ks * 4 + l4) ^ bsw[ni]) << 3)]; \
} while (0)
#define MMA(qm, qn) do { \
    __builtin_amdgcn_s_setprio(1); \
    _Pragma("unroll") for (int ks = 0; ks < 2; ks++) \
    _Pragma("unroll") for (int mi = 0; mi < 4; mi++) \
    _Pragma("unroll") for (int ni = 0; ni < 2; ni++) \
        acc[qm][qn][mi][ni] = __builtin_amdgcn_mfma_f32_16x16x32_bf16( \
            aF[mi][ks], bF[qn][ni][ks], acc[qm][qn][mi][ni], 0, 0, 0); \
    __builtin_amdgcn_s_setprio(0); \
} while (0)

    // prologue: stage tile0 + first half-pair of tile1, full drain, barrier.
    STAGE(0, 0, 0);   // A0(0)
    STAGE(0, 1, 1);   // B1(0)
    STAGE(0, 0, 1);   // B0(0)
    STAGE(0, 1, 0);   // A1(0)
    STAGE(1, 0, 0);   // A0(1)
    STAGE(1, 1, 1);   // B1(1)
    WAITV(0);
    BARR();

    for (int tt = 0; tt < NT; tt++) {
        const int cb = (tt & 1) * 32768;
        // ---- phase 0: quadrant (0,0) ----   [A0(tt),B0(tt) drained pre-barrier]
        LOAD_A(0); LOAD_B(0);                        // 12 ds_read_b128
        if (tt + 1 < NT) STAGE(tt + 1, 0, 1);        // B0(t+1)
        BARR();
        MMA(0, 0);
        BARR();
        // ---- phase 1: quadrant (0,1) ----   [B1(tt) drained pre-barrier]
        LOAD_B(1);                                   // 4 ds_read_b128
        if (tt + 1 < NT) STAGE(tt + 1, 1, 0);        // A1(t+1)
        BARR();
        MMA(0, 1);
        if (tt + 1 < NT) { WAITV(8); } else { WAITV(0); }  // drain A1(tt)
        BARR();
        // ---- phase 2: quadrant (1,1) ----
        LOAD_A(1);                                   // 8 ds_read_b128
        if (tt + 2 < NT) STAGE(tt + 2, 0, 0);        // A0(t+2)
        BARR();
        MMA(1, 1);
        BARR();
        // ---- phase 3: quadrant (1,0) ----
        if (tt + 2 < NT) STAGE(tt + 2, 1, 1);        // B1(t+2)
        BARR();
        MMA(1, 0);
        if (tt + 2 < NT)      { WAITV(6); }          // drain A0,B0(tt+1)
        else if (tt + 1 < NT) { WAITV(2); }
        BARR();
    }

#undef LOAD_A
#undef LOAD_B
#undef MMA

    // Epilogue. 16x16 C/D: col = lane&15, row = (lane>>4)*4 + reg
    if (Cb) {
        unsigned short* Cz = Cb + (long long)blockIdx.z * sC;
#pragma unroll
        for (int qm = 0; qm < 2; qm++)
#pragma unroll
        for (int qn = 0; qn < 2; qn++)
#pragma unroll
        for (int mi = 0; mi < 4; mi++)
#pragma unroll
        for (int ni = 0; ni < 2; ni++) {
            const int rb = m0 + qm * 128 + wm + mi * 16 + l4 * 4;
            const int cc = n0 + qn * 128 + wn + ni * 16 + l15;
#pragma unroll
            for (int rr = 0; rr < 4; rr++)
                Cz[(size_t)(rb + rr) * ldc + cc] = f2bf(acc[qm][qn][mi][ni][rr]);
        }
    } else {
        float* Cz = Cf + (long long)blockIdx.z * sC;
#pragma unroll
        for (int qm = 0; qm < 2; qm++)
#pragma unroll
        for (int qn = 0; qn < 2; qn++)
#pragma unroll
        for (int mi = 0; mi < 4; mi++)
#pragma unroll
        for (int ni = 0; ni < 2; ni++) {
            const int rb = m0 + qm * 128 + wm + mi * 16 + l4 * 4;
            const int cc = n0 + qn * 128 + wn + ni * 16 + l15;
#pragma unroll
            for (int rr = 0; rr < 4; rr++)
                Cz[(size_t)(rb + rr) * ldc + cc] = acc[qm][qn][mi][ni][rr];
        }
    }
}

// ---------------------------------------------------------------------------
// bf16 MFMA NT GEMM, 32x32x16 MFMA, BK=64, XOR bank swizzle.
// Proven: 0 bank conflicts, ~3 blocks/CU, graceful tail on 1056-block grids.
// xswz: measured REGRESSION on GEMM1 (R6: FETCH -40% but dur +4% — kernel is
// latency/drain-bound, not fetch-bound). Kept as a parameter, always 0.
// ---------------------------------------------------------------------------
__global__ __launch_bounds__(256) void gemm_bt_mfma(
    const unsigned short* __restrict__ A, int lda, long long sA,
    const unsigned short* __restrict__ B, int ldb, long long sB,
    float* __restrict__ Cf, unsigned short* __restrict__ Cb, int ldc,
    long long sC, int K, int mswap, int xswz)
{
    __shared__ unsigned short As[128 * 64];   // 16 KB
    __shared__ unsigned short Bs[128 * 64];   // 16 KB
    A += (long long)blockIdx.z * sA;
    B += (long long)blockIdx.z * sB;
    const int t     = threadIdx.x;
    int bx = blockIdx.x, by = blockIdx.y;
    if (xswz) {
        const int gx  = gridDim.x;
        const int nwg = gx * gridDim.y;
        const int bid = by * gx + bx;                 // natural order, x-fastest
        const int tl  = (bid & 7) * (nwg >> 3) + (bid >> 3);  // bijective: nwg%8==0
        bx = tl % gx;
        by = tl / gx;
    }
    const int m0    = (mswap ? bx : by) * 128;
    const int n0    = (mswap ? by : bx) * 128;
    const int w     = t >> 6;
    const int lane  = t & 63;
    const int col   = lane & 31;
    const int khalf = lane >> 5;
    const int wm    = (w & 1) * 64;
    const int wn    = (w >> 1) * 64;

    const int srow  = t >> 3;
    const int sslot = t & 7;
    const unsigned short* Agp[4];
    const unsigned short* Bgp[4];
#pragma unroll
    for (int i = 0; i < 4; i++) {
        const int r   = srow + 32 * i;
        const int gch = sslot ^ ((r ^ (r >> 3)) & 7);
        Agp[i] = A + (size_t)(m0 + r) * lda + gch * 8;
        Bgp[i] = B + (size_t)(n0 + r) * ldb + gch * 8;
    }
    unsigned short* Asl = &As[t * 8];
    unsigned short* Bsl = &Bs[t * 8];

    int aOff[2], aXor[2], bOff[2], bXor[2];
#pragma unroll
    for (int i = 0; i < 2; i++) {
        const int ra = wm + i * 32 + col;
        aOff[i] = ra * 64; aXor[i] = (ra ^ (ra >> 3)) & 7;
        const int rb = wn + i * 32 + col;
        bOff[i] = rb * 64; bXor[i] = (rb ^ (rb >> 3)) & 7;
    }

    f32x16 acc[2][2];
#pragma unroll
    for (int mi = 0; mi < 2; mi++)
#pragma unroll
        for (int ni = 0; ni < 2; ni++)
#pragma unroll
            for (int e = 0; e < 16; e++) acc[mi][ni][e] = 0.f;

    for (int k0 = 0; k0 < K; k0 += 64) {
        __syncthreads();
#pragma unroll
        for (int i = 0; i < 4; i++) {
            gl_lds16(Agp[i] + k0, Asl + i * 2048);
            gl_lds16(Bgp[i] + k0, Bsl + i * 2048);
        }
        __syncthreads();
#pragma unroll
        for (int ks = 0; ks < 4; ks++) {
            const int ch = ks * 2 + khalf;
            bf16x8 af[2], bfr[2];
#pragma unroll
            for (int i = 0; i < 2; i++) {
                af[i]  = *(const bf16x8*)&As[aOff[i] + ((ch ^ aXor[i]) * 8)];
                bfr[i] = *(const bf16x8*)&Bs[bOff[i] + ((ch ^ bXor[i]) * 8)];
            }
#pragma unroll
            for (int mi = 0; mi < 2; mi++)
#pragma unroll
                for (int ni = 0; ni < 2; ni++)
                    acc[mi][ni] = __builtin_amdgcn_mfma_f32_32x32x16_bf16(
                        af[mi], bfr[ni], acc[mi][ni], 0, 0, 0);
        }
    }

    // Epilogue. 32x32 C/D: col = lane&31, row = (reg&3) + 8*(reg>>2) + 4*(lane>>5)
    if (Cb) {
#pragma unroll
        for (int mi = 0; mi < 2; mi++)
#pragma unroll
            for (int ni = 0; ni < 2; ni++) {
                const int rbase = m0 + wm + mi * 32 + 4 * khalf;
                const int cc    = n0 + wn + ni * 32 + col;
#pragma unroll
                for (int g = 0; g < 4; g++)
#pragma unroll
                    for (int rr = 0; rr < 4; rr++)
                        Cb[(size_t)(rbase + 8 * g + rr) * ldc + cc] =
                            f2bf(acc[mi][ni][4 * g + rr]);
            }
    } else {
        float* Cz = Cf + (long long)blockIdx.z * sC;
#pragma unroll
        for (int mi = 0; mi < 2; mi++)
#pragma unroll
            for (int ni = 0; ni < 2; ni++) {
                const int rbase = m0 + wm + mi * 32 + 4 * khalf;
                const int cc    = n0 + wn + ni * 32 + col;
#pragma unroll
                for (int g = 0; g < 4; g++)
#pragma unroll
                    for (int rr = 0; rr < 4; rr++)
                        Cz[(size_t)(rbase + 8 * g + rr) * ldc + cc] =
                            acc[mi][ni][4 * g + rr];
            }
    }
}

// ---------------------------------------------------------------------------
// out = p0+p1+p2+p3 (fp32) — split-K=4 reduce for GEMM2
// ---------------------------------------------------------------------------
__global__ __launch_bounds__(256) void addf4_kernel(
    const float* __restrict__ p, float* __restrict__ o)
{
    size_t i = ((size_t)blockIdx.x * 256 + threadIdx.x) * 4;
    float4 a = *(const float4*)(p + i);
    float4 b = *(const float4*)(p + i + 4194304);
    float4 c = *(const float4*)(p + i + 8388608);
    float4 d = *(const float4*)(p + i + 12582912);
    float4 r = make_float4(a.x + b.x + c.x + d.x, a.y + b.y + c.y + d.y,
                           a.z + b.z + c.z + d.z, a.w + b.w + c.w + d.w);
    *(float4*)(o + i) = r;
}

// ---------------------------------------------------------------------------
// fp32 NT GEMM (dt split-K only)
// ---------------------------------------------------------------------------
__global__ __launch_bounds__(256) void gemm_nt(
    const float* __restrict__ A, int lda, long long sA,
    const float* __restrict__ B, int ldb, long long sB,
    float* __restrict__ C, int ldc, long long sC, int K)
{
    A += (long long)blockIdx.z * sA;
    B += (long long)blockIdx.z * sB;
    C += (long long)blockIdx.z * sC;
    const int t  = threadIdx.x;
    const int m0 = blockIdx.y * 128;
    const int n0 = blockIdx.x * 64;
    __shared__ float As[16][132];
    __shared__ float Bs[16][68];
    const int tx = t & 15;
    const int ty = t >> 4;

    const int arow = t & 127;
    const int akh  = (t >> 7) * 8;
    const float* Aload = A + (size_t)(m0 + arow) * (size_t)lda + akh;
    const int brow = t & 63;
    const int bk4  = (t >> 6) * 4;
    const float* Bload = B + (size_t)(n0 + brow) * (size_t)ldb + bk4;

    float acc[8][4];
#pragma unroll
    for (int i = 0; i < 8; i++)
#pragma unroll
        for (int j = 0; j < 4; j++) acc[i][j] = 0.f;

    for (int k0 = 0; k0 < K; k0 += 16) {
        __syncthreads();
        float4 a0 = *(const float4*)(Aload + k0);
        float4 a1 = *(const float4*)(Aload + k0 + 4);
        float4 b0 = *(const float4*)(Bload + k0);
        As[akh + 0][arow] = a0.x; As[akh + 1][arow] = a0.y;
        As[akh + 2][arow] = a0.z; As[akh + 3][arow] = a0.w;
        As[akh + 4][arow] = a1.x; As[akh + 5][arow] = a1.y;
        As[akh + 6][arow] = a1.z; As[akh + 7][arow] = a1.w;
        Bs[bk4 + 0][brow] = b0.x; Bs[bk4 + 1][brow] = b0.y;
        Bs[bk4 + 2][brow] = b0.z; Bs[bk4 + 3][brow] = b0.w;
        __syncthreads();
#pragma unroll
        for (int k = 0; k < 16; k++) {
            float4 a4 = *(const float4*)(&As[k][ty * 8]);
            float4 a5 = *(const float4*)(&As[k][ty * 8 + 4]);
            float4 b4 = *(const float4*)(&Bs[k][tx * 4]);
            float am[8] = {a4.x, a4.y, a4.z, a4.w, a5.x, a5.y, a5.z, a5.w};
            float bn[4] = {b4.x, b4.y, b4.z, b4.w};
#pragma unroll
            for (int i = 0; i < 8; i++)
#pragma unroll
                for (int j = 0; j < 4; j++) acc[i][j] += am[i] * bn[j];
        }
    }
#pragma unroll
    for (int i = 0; i < 8; i++) {
        float4 o = make_float4(acc[i][0], acc[i][1], acc[i][2], acc[i][3]);
        *(float4*)(C + (size_t)(m0 + ty * 8 + i) * (size_t)ldc + n0 + tx * 4) = o;
    }
}

// ---------------------------------------------------------------------------
__global__ __launch_bounds__(256) void dt_reduce_kernel(
    const float* __restrict__ part, const float* __restrict__ dt_bias,
    float* __restrict__ dtg)
{
    const int i = blockIdx.x * 256 + threadIdx.x;
    float x = dt_bias[i & 63];
#pragma unroll
    for (int z = 0; z < 32; z++) x += part[(size_t)z * 131072 + i];
    dtg[i] = (x > 20.f) ? x : log1pf(__expf(x));
}

// ---------------------------------------------------------------------------
// Causal depthwise conv (K=4) + bias + SiLU, 8 outputs/thread along s.
// ---------------------------------------------------------------------------
__global__ __launch_bounds__(256) void conv_silu8_kernel(
    const unsigned short* __restrict__ projbf, const float* __restrict__ conv_w,
    const float* __restrict__ conv_b, unsigned short* __restrict__ out)
{
    const int c  = blockIdx.x * 256 + threadIdx.x;   // [0, 4352)
    const int s0 = blockIdx.y * 8;
    const float4 w = *(const float4*)(conv_w + (size_t)c * 4);
    const float b = conv_b[c];
    const size_t base = 4096 + (size_t)c;
    float v[11];
#pragma unroll
    for (int m = 0; m < 11; m++) {
        int s = s0 - 3 + m;
        v[m] = (s >= 0) ? bf2f(projbf[(size_t)s * GEMM1N + base]) : 0.f;
    }
#pragma unroll
    for (int j = 0; j < 8; j++) {
        float acc = b + v[j] * w.x + v[j + 1] * w.y + v[j + 2] * w.z + v[j + 3] * w.w;
        float sig = 1.f / (1.f + __expf(-acc));
        out[(size_t)(s0 + j) * CONVD + c] = f2bf(acc * sig);
    }
}

// ---------------------------------------------------------------------------
// SSM core, MFMA, bf16 hBC input (unchanged)
// ---------------------------------------------------------------------------
__global__ __launch_bounds__(256, 2) void ssm_mfma_kernel(
    const unsigned short* __restrict__ hBC, const float* __restrict__ dtg,
    const float* __restrict__ Gm, const float* __restrict__ A_log,
    const float* __restrict__ Dp, float* __restrict__ y)
{
    const int h    = blockIdx.x;
    const int c    = blockIdx.y;
    const int t    = threadIdx.x;
    const int wid  = t >> 6;
    const int lane = t & 63;
    const int lo   = lane & 15;
    const int q    = lane >> 4;

    __shared__ float sAcum[CS], sdt[CS], sD[CS], sEs[CS], sDecay[CS], sScl[CS];
    __shared__ float sWaveSum[4];
    __shared__ unsigned short sHdtT[64 * 264];
    __shared__ unsigned short sStT[64 * 136];
    __shared__ unsigned short sBufB[128 * 72];

    const float A = -__expf(A_log[h]);
    const int row0 = c * CS;
    const unsigned short* hid = hBC + (size_t)row0 * CONVD + h * P_DIM;
    const unsigned short* Bp  = hBC + (size_t)row0 * CONVD + INTER;
    const unsigned short* Cp  = hBC + (size_t)row0 * CONVD + INTER + N_DIM;
    const float* gm = Gm + (size_t)c * CS * CS;

    float dtv = dtg[(size_t)(row0 + t) * NH + h];
    float v = A * dtv;
    for (int off = 1; off < 64; off <<= 1) {
        float u = __shfl_up(v, off, 64);
        if (lane >= off) v += u;
    }
    if (lane == 63) sWaveSum[wid] = v;
    __syncthreads();
    float pre = 0.f;
    for (int i = 0; i < 4; i++) if (i < wid) pre += sWaveSum[i];
    v += pre;
    sAcum[t] = v;
    sdt[t] = dtv;
    __syncthreads();
    const float AcumEnd = sAcum[CS - 1];
    {
        float ac   = sAcum[t];
        float apre = (t < 64) ? 0.f : sAcum[(t & ~63) - 1];
        sD[t]     = __expf(ac - apre);
        sEs[t]    = __expf(sAcum[t | 63] - ac);
        sDecay[t] = __expf(AcumEnd - ac);
        sScl[t]   = __expf(ac);
    }

    unsigned short* stgu = sStT;
    for (int lt = 0; lt < 4; lt++) {
        __syncthreads();
        {
            const int c8 = (t & 7) * 8;
#pragma unroll
            for (int j = 0; j < 2; j++) {
                int l = (t >> 3) + 32 * j;
                *(uint4*)&stgu[l * 64 + c8] =
                    *(const uint4*)(hid + (size_t)(lt * 64 + l) * CONVD + c8);
            }
        }
        __syncthreads();
        {
            const int p = t & 63, lq = (t >> 6) * 16;
#pragma unroll
            for (int j = 0; j < 4; j++) {
                ushort4 pk;
                int l0 = lq + j * 4;
                pk.x = f2bf(bf2f(stgu[(l0 + 0) * 64 + p]) * sdt[lt * 64 + l0 + 0]);
                pk.y = f2bf(bf2f(stgu[(l0 + 1) * 64 + p]) * sdt[lt * 64 + l0 + 1]);
                pk.z = f2bf(bf2f(stgu[(l0 + 2) * 64 + p]) * sdt[lt * 64 + l0 + 2]);
                pk.w = f2bf(bf2f(stgu[(l0 + 3) * 64 + p]) * sdt[lt * 64 + l0 + 3]);
                *(uint2*)&sHdtT[p * 264 + lt * 64 + l0] = *(uint2*)&pk;
            }
        }
    }

    f32x4 acc2[2][4];
#pragma unroll
    for (int mi = 0; mi < 2; mi++)
#pragma unroll
        for (int ni = 0; ni < 4; ni++) acc2[mi][ni] = (f32x4){0.f, 0.f, 0.f, 0.f};
    const int psub = (wid & 1) * 32;
    const int nsub = (wid >> 1) * 64;

    for (int qt = 0; qt < 4; qt++) {
        for (int hf = 0; hf < 2; hf++) {
            __syncthreads();
            {
                const int n8 = (t & 15) * 8;
#pragma unroll
                for (int j = 0; j < 2; j++) {
                    int r = (t >> 4) + 16 * j;
                    *(uint4*)&stgu[r * 128 + n8] =
                        *(const uint4*)(Bp + (size_t)(qt * 64 + hf * 32 + r) * CONVD + n8);
                }
            }
            __syncthreads();
            {
                const int n = t & 127, lc = (t >> 7) * 16;
#pragma unroll
                for (int j = 0; j < 4; j++) {
                    int l0 = lc + j * 4;
                    ushort4 pk;
                    pk.x = f2bf(bf2f(stgu[(l0 + 0) * 128 + n]) * sDecay[qt * 64 + hf * 32 + l0 + 0]);
                    pk.y = f2bf(bf2f(stgu[(l0 + 1) * 128 + n]) * sDecay[qt * 64 + hf * 32 + l0 + 1]);
                    pk.z = f2bf(bf2f(stgu[(l0 + 2) * 128 + n]) * sDecay[qt * 64 + hf * 32 + l0 + 2]);
                    pk.w = f2bf(bf2f(stgu[(l0 + 3) * 128 + n]) * sDecay[qt * 64 + hf * 32 + l0 + 3]);
                    *(uint2*)&sBufB[n * 72 + hf * 32 + l0] = *(uint2*)&pk;
                }
            }
        }
        __syncthreads();
#pragma unroll
        for (int ks = 0; ks < 2; ks++) {
            const int k0 = qt * 64 + ks * 32;
            const int kq = ks * 32;
            bf16x8 a2[2], b2[4];
#pragma unroll
            for (int mi = 0; mi < 2; mi++)
                a2[mi] = *(const bf16x8*)&sHdtT[(psub + mi * 16 + lo) * 264 + k0 + q * 8];
#pragma unroll
            for (int ni = 0; ni < 4; ni++)
                b2[ni] = *(const bf16x8*)&sBufB[(nsub + ni * 16 + lo) * 72 + kq + q * 8];
#pragma unroll
            for (int mi = 0; mi < 2; mi++)
#pragma unroll
                for (int ni = 0; ni < 4; ni++)
                    acc2[mi][ni] = __builtin_amdgcn_mfma_f32_16x16x32_bf16(
                        a2[mi], b2[ni], acc2[mi][ni], 0, 0, 0);
        }
    }
    __syncthreads();
#pragma unroll
    for (int mi = 0; mi < 2; mi++)
#pragma unroll
        for (int ni = 0; ni < 4; ni++)
#pragma unroll
            for (int rr = 0; rr < 4; rr++) {
                int p = psub + mi * 16 + q * 4 + rr;
                int n = nsub + ni * 16 + lo;
                sStT[p * 136 + n] = f2bf(acc2[mi][ni][rr]);
            }

    f32x4 accY[4][2][2];
#pragma unroll
    for (int i = 0; i < 4; i++)
#pragma unroll
        for (int mi = 0; mi < 2; mi++)
#pragma unroll
            for (int pi = 0; pi < 2; pi++) accY[i][mi][pi] = (f32x4){0.f, 0.f, 0.f, 0.f};
    const int pcol = (wid & 1) * 32;
    const int rsub = (wid >> 1) * 16;
    unsigned short* Cs = sBufB;

    for (int i = 0; i < 4; i++) {
        __syncthreads();
        {
            const int n8 = (t & 15) * 8;
#pragma unroll
            for (int j = 0; j < 4; j++) {
                int r = (t >> 4) + 16 * j;
                uint4 cv = *(const uint4*)(Cp + (size_t)(i * 64 + r) * CONVD + n8);
                float scl = sScl[i * 64 + r];
                const unsigned short* cu = (const unsigned short*)&cv;
                ushort4 p0, p1;
                p0.x = f2bf(bf2f(cu[0]) * scl); p0.y = f2bf(bf2f(cu[1]) * scl);
                p0.z = f2bf(bf2f(cu[2]) * scl); p0.w = f2bf(bf2f(cu[3]) * scl);
                p1.x = f2bf(bf2f(cu[4]) * scl); p1.y = f2bf(bf2f(cu[5]) * scl);
                p1.z = f2bf(bf2f(cu[6]) * scl); p1.w = f2bf(bf2f(cu[7]) * scl);
                *(uint2*)&Cs[r * 136 + n8]     = *(uint2*)&p0;
                *(uint2*)&Cs[r * 136 + n8 + 4] = *(uint2*)&p1;
            }
        }
        __syncthreads();
#pragma unroll
        for (int ks = 0; ks < 4; ks++) {
            const int k0 = ks * 32;
            bf16x8 a3[2], b3[2];
#pragma unroll
            for (int mi = 0; mi < 2; mi++)
                a3[mi] = *(const bf16x8*)&Cs[(mi * 32 + rsub + lo) * 136 + k0 + q * 8];
#pragma unroll
            for (int pi = 0; pi < 2; pi++)
                b3[pi] = *(const bf16x8*)&sStT[(pcol + pi * 16 + lo) * 136 + k0 + q * 8];
#pragma unroll
            for (int mi = 0; mi < 2; mi++)
#pragma unroll
                for (int pi = 0; pi < 2; pi++)
                    accY[i][mi][pi] = __builtin_amdgcn_mfma_f32_16x16x32_bf16(
                        a3[mi], b3[pi], accY[i][mi][pi], 0, 0, 0);
        }
    }

    unsigned short* Mt = sBufB;
    for (int i = 0; i < 4; i++) {
        const int nk = 2 * (i + 1);
        for (int mi = 0; mi < 2; mi++) {
            __syncthreads();
            if (wid <= i) {
                float P = 1.f;
                for (int m = wid + 1; m <= i - 1; m++) P *= sD[m * 64 + 63];
                const int s4 = wid * 64 + lo * 4;
                float4 es4 = *(const float4*)&sEs[s4];
#pragma unroll
                for (int j = 0; j < 8; j++) {
                    int lr = q + j * 4;
                    int l  = i * 64 + mi * 32 + lr;
                    float4 g4 = *(const float4*)&gm[(size_t)l * CS + s4];
                    float w0, w1, w2, w3;
                    if (wid == i) {
                        float al = sAcum[l];
                        w0 = (s4 + 0 <= l) ? __expf(al - sAcum[s4 + 0]) : 0.f;
                        w1 = (s4 + 1 <= l) ? __expf(al - sAcum[s4 + 1]) : 0.f;
                        w2 = (s4 + 2 <= l) ? __expf(al - sAcum[s4 + 2]) : 0.f;
                        w3 = (s4 + 3 <= l) ? __expf(al - sAcum[s4 + 3]) : 0.f;
                    } else {
                        float rs = sD[l] * P;
                        w0 = rs * es4.x; w1 = rs * es4.y;
                        w2 = rs * es4.z; w3 = rs * es4.w;
                    }
                    ushort4 pk;
                    pk.x = f2bf(g4.x * w0); pk.y = f2bf(g4.y * w1);
                    pk.z = f2bf(g4.z * w2); pk.w = f2bf(g4.w * w3);
                    *(uint2*)&Mt[lr * 264 + s4] = *(uint2*)&pk;
                }
            }
            __syncthreads();
            for (int ks = 0; ks < nk; ks++) {
                const int k0 = ks * 32;
                bf16x8 am = *(const bf16x8*)&Mt[(rsub + lo) * 264 + k0 + q * 8];
                bf16x8 b1[2];
#pragma unroll
                for (int pi = 0; pi < 2; pi++)
                    b1[pi] = *(const bf16x8*)&sHdtT[(pcol + pi * 16 + lo) * 264 + k0 + q * 8];
#pragma unroll
                for (int pi = 0; pi < 2; pi++)
                    accY[i][mi][pi] = __builtin_amdgcn_mfma_f32_16x16x32_bf16(
                        am, b1[pi], accY[i][mi][pi], 0, 0, 0);
            }
        }
    }

    const float Dh = Dp[h];
#pragma unroll
    for (int i = 0; i < 4; i++)
#pragma unroll
        for (int mi = 0; mi < 2; mi++)
#pragma unroll
            for (int pi = 0; pi < 2; pi++)
#pragma unroll
                for (int rr = 0; rr < 4; rr++) {
                    int l = i * 64 + mi * 32 + rsub + q * 4 + rr;
                    int p = pcol + pi * 16 + lo;
                    float hv = bf2f(hid[(size_t)l * CONVD + p]);
                    y[(size_t)(row0 + l) * INTER + h * P_DIM + p] =
                        accY[i][mi][pi][rr] + Dh * hv;
                }
}

// ---------------------------------------------------------------------------
// Gated RMSNorm (unchanged)
// ---------------------------------------------------------------------------
__global__ __launch_bounds__(256) void norm_kernel(
    const float* __restrict__ y, const unsigned short* __restrict__ projbf,
    const float* __restrict__ norm_w, unsigned short* __restrict__ yn)
{
    const int s = blockIdx.x;
    const int t = threadIdx.x;
    __shared__ float sYf[INTER];
    __shared__ float sW[4];
    const float* yrow = y + (size_t)s * INTER;
    const unsigned short* grow = projbf + (size_t)s * GEMM1N;
    float sum = 0.f;
    for (int j0 = 0; j0 < INTER; j0 += 2048) {
        int j = j0 + t * 8;
        float4 y0 = *(const float4*)(yrow + j);
        float4 y1 = *(const float4*)(yrow + j + 4);
        uint4 gp = *(const uint4*)(grow + j);
        float gv[8] = {
            bf2f((unsigned short)(gp.x & 0xffff)), bf2f((unsigned short)(gp.x >> 16)),
            bf2f((unsigned short)(gp.y & 0xffff)), bf2f((unsigned short)(gp.y >> 16)),
            bf2f((unsigned short)(gp.z & 0xffff)), bf2f((unsigned short)(gp.z >> 16)),
            bf2f((unsigned short)(gp.w & 0xffff)), bf2f((unsigned short)(gp.w >> 16))};
        float yv8[8] = {y0.x, y0.y, y0.z, y0.w, y1.x, y1.y, y1.z, y1.w};
#pragma unroll
        for (int e = 0; e < 8; e++) {
            float f = yv8[e] * (gv[e] / (1.f + __expf(-gv[e])));
            sum += f * f;
            sYf[j + e] = f;
        }
    }
    for (int off = 32; off > 0; off >>= 1) sum += __shfl_down(sum, off, 64);
    if ((t & 63) == 0) sW[t >> 6] = sum;
    __syncthreads();
    const float var = (sW[0] + sW[1] + sW[2] + sW[3]) * (1.f / (float)INTER);
    const float rs = rsqrtf(var + EPS);
    for (int j0 = 0; j0 < INTER; j0 += 2048) {
        int j = j0 + t * 8;
        float4 w0 = *(const float4*)(norm_w + j);
        float4 w1 = *(const float4*)(norm_w + j + 4);
        float wv[8] = {w0.x, w0.y, w0.z, w0.w, w1.x, w1.y, w1.z, w1.w};
        unsigned short o[8];
#pragma unroll
        for (int e = 0; e < 8; e++) o[e] = f2bf(sYf[j + e] * wv[e] * rs);
        uint4 ov;
        ov.x = (unsigned int)o[0] | ((unsigned int)o[1] << 16);
        ov.y = (unsigned int)o[2] | ((unsigned int)o[3] << 16);
        ov.z = (unsigned int)o[4] | ((unsigned int)o[5] << 16);
        ov.w = (unsigned int)o[6] | ((unsigned int)o[7] << 16);
        *(uint4*)(yn + (size_t)s * INTER + j) = ov;
    }
}

// ---------------------------------------------------------------------------
extern "C" void kernel_launch(void* const* d_in, const int* in_sizes, int n_in,
                              void* d_out, int out_size, void* d_ws, size_t ws_size,
                              hipStream_t stream)
{
    const float* X       = (const float*)d_in[0];
    const float* W_in    = (const float*)d_in[2];
    const float* conv_w  = (const float*)d_in[3];
    const float* conv_b  = (const float*)d_in[4];
    const float* dt_bias = (const float*)d_in[5];
    const float* A_log   = (const float*)d_in[6];
    const float* Dp      = (const float*)d_in[7];
    const float* norm_w  = (const float*)d_in[8];
    const float* W_out   = (const float*)d_in[9];
    float* out = (float*)d_out;
    float* ws  = (float*)d_ws;

    unsigned short* projbf = (unsigned short*)(ws + OFF_PROJBF);
    unsigned short* hbc16  = (unsigned short*)(ws + OFF_HBC);
    float* dtg     = ws + OFF_DTG;
    float* dtpart  = ws + OFF_DTPART;
    float* gm      = ws + OFF_GM;
    float* yv      = ws + OFF_YV;
    unsigned short* Xbf    = (unsigned short*)(ws + OFF_R);
    unsigned short* Winbf  = (unsigned short*)(ws + OFF_R + 2097152);
    unsigned short* ynbf   = (unsigned short*)(ws + OFF_R);   // aliases Xbf (post-GEMM1)
    unsigned short* Woutbf = (unsigned short*)(ws + OFF_WOUT);
    float* part = ws;   // GEMM2 split-K=4 fp32 partials: ws[0 .. 16,777,216)

    // all three casts in one launch
    cast3_kernel<<<14592, 256, 0, stream>>>(X, W_in, W_out, Xbf, Winbf, Woutbf);

    // GEMM1: proven 128^2 kernel, natural block order (xswz=0)
    gemm_bt_mfma<<<dim3(S_LEN / 128, GEMM1N / 128, 1), 256, 0, stream>>>(
        Xbf, E_DIM, 0LL, Winbf, E_DIM, 0LL, nullptr, projbf, GEMM1N, 0LL,
        E_DIM, 1, 0);

    // dt columns fp32, split-K=32 (512 blocks)
    gemm_nt<<<dim3(1, 16, 32), 256, 0, stream>>>(
        X, E_DIM, 64LL, W_in + (size_t)GEMM1N * E_DIM, E_DIM, 64LL,
        dtpart, NH, 131072LL, 64);
    dt_reduce_kernel<<<512, 256, 0, stream>>>(dtpart, dt_bias, dtg);

    // conv + silu -> bf16 hBC
    conv_silu8_kernel<<<dim3(CONVD / 256, S_LEN / 8), 256, 0, stream>>>(
        projbf, conv_w, conv_b, hbc16);

    // Gm[c] = Cm_c @ Bm_c^T via bf16 MFMA (fp32 out) — K=128, no swizzle
    gemm_bt_mfma<<<dim3(CS / 128, CS / 128, NCHUNK), 256, 0, stream>>>(
        hbc16 + INTER + N_DIM, CONVD, (long long)CS * CONVD,
        hbc16 + INTER,         CONVD, (long long)CS * CONVD,
        gm, nullptr, CS, (long long)CS * CS, N_DIM, 0, 0);

    ssm_mfma_kernel<<<dim3(NH, NCHUNK), 256, 0, stream>>>(
        hbc16, dtg, gm, A_log, Dp, yv);

    norm_kernel<<<dim3(S_LEN), 256, 0, stream>>>(yv, projbf, norm_w, ynbf);

    // GEMM2: 256x256 8-phase (race-fixed), split-K=4 -> 256 blocks;
    // fp32 partials (64B-line stores; bf16 partials were an R7 regression).
    gemm256_8ph<<<dim3(E_DIM / 256, S_LEN / 256, 4), 512, 0, stream>>>(
        ynbf, INTER, 1024LL, Woutbf, INTER, 1024LL,
        part, nullptr, E_DIM, 4194304LL, 1024, 0);
    addf4_kernel<<<4096, 256, 0, stream>>>(part, out);
}

// Round 9
// 414.880 us; speedup vs baseline: 1.0064x; 1.0064x over previous
//
#include <hip/hip_runtime.h>
#include <math.h>

// Problem constants
#define S_LEN   2048
#define E_DIM   2048
#define NH      64
#define P_DIM   64
#define N_DIM   128
#define CS      256
#define NCHUNK  8
#define INTER   4096
#define CONVD   4352
#define PROJ    8512
#define GEMM1N  8448       // INTER + CONVD = 66*128 = 33*256 exactly
#define EPS     1e-5f

// Workspace layout (float units)
#define OFF_PROJBF 0ull                        // bf16 2048*8448 = 8,650,752 fl
#define OFF_HBC    8650752ull                  // bf16 2048*4352 = 4,456,448 fl
#define OFF_DTG    13107200ull                 // fp32 2048*64   =   131,072 fl
#define OFF_DTPART 13238272ull                 // fp32 32*2048*64 = 4,194,304 fl
#define OFF_GM     17432576ull                 // fp32 8*256*256 =   524,288 fl
#define OFF_YV     17956864ull                 // fp32 2048*4096 = 8,388,608 fl
#define OFF_R      26345472ull                 // Xbf(2,097,152 fl) + Winbf(8,650,752 fl)
#define OFF_WOUT   37093376ull                 // bf16 2048*4096 = 2,097,152 fl
// ws end = 39,190,528 fl = 156.8 MB.
// ynbf aliases Xbf (R+0) — written by norm, after GEMM1's last read of Xbf.
// GEMM2 split-K=4 partials: 4 x 4,194,304 fl FP32 at ws[0 .. 16,777,216).

typedef __bf16 bf16x8 __attribute__((ext_vector_type(8)));
typedef float  f32x4  __attribute__((ext_vector_type(4)));
typedef float  f32x16 __attribute__((ext_vector_type(16)));

__device__ __forceinline__ float bf2f(unsigned short u) {
    union { unsigned int i; float f; } v; v.i = ((unsigned int)u) << 16; return v.f;
}
__device__ __forceinline__ unsigned short f2bf(float f) {
    union { float f; unsigned int i; } v; v.f = f;
    unsigned int r = v.i + 0x7FFFu + ((v.i >> 16) & 1u);
    return (unsigned short)(r >> 16);
}
__device__ __forceinline__ void gl_lds16(const void* g, void* l) {
    __builtin_amdgcn_global_load_lds(
        (const __attribute__((address_space(1))) void*)g,
        (__attribute__((address_space(3))) void*)l, 16, 0, 0);
}

// ---------------------------------------------------------------------------
// merged fp32 -> bf16 cast of X / W_in[0:8448] / W_out (one launch)
// ---------------------------------------------------------------------------
__global__ __launch_bounds__(256) void cast3_kernel(
    const float* __restrict__ X, const float* __restrict__ Win,
    const float* __restrict__ Wout, unsigned short* __restrict__ Xbf,
    unsigned short* __restrict__ Winbf, unsigned short* __restrict__ Woutbf)
{
    const int blk = blockIdx.x;
    const float* src; unsigned short* dst; size_t off;
    if (blk < 2048)       { src = X;    dst = Xbf;    off = (size_t)blk * 2048; }
    else if (blk < 10496) { src = Win;  dst = Winbf;  off = (size_t)(blk - 2048) * 2048; }
    else                  { src = Wout; dst = Woutbf; off = (size_t)(blk - 10496) * 2048; }
    size_t i = off + (size_t)threadIdx.x * 8;
    float4 a = *(const float4*)(src + i);
    float4 b = *(const float4*)(src + i + 4);
    uint4 o;
    o.x = (unsigned int)f2bf(a.x) | ((unsigned int)f2bf(a.y) << 16);
    o.y = (unsigned int)f2bf(a.z) | ((unsigned int)f2bf(a.w) << 16);
    o.z = (unsigned int)f2bf(b.x) | ((unsigned int)f2bf(b.y) << 16);
    o.w = (unsigned int)f2bf(b.z) | ((unsigned int)f2bf(b.w) << 16);
    *(uint4*)(dst + i) = o;
}

// ---------------------------------------------------------------------------
// 256x256 8-phase bf16 NT GEMM (HK-style schedule, plain HIP).
// Used ONLY where the grid is exactly <=256 blocks (GEMM2: 8x8x4).
// RACE-FIXED gates (R5/R6, tripwire-verified): vmcnt is PER-WAVE; a
// half-tile is staged by all 8 waves cooperatively, so every gate is
// wait -> BARRIER -> read.
// ---------------------------------------------------------------------------
#define WAITV(n) asm volatile("s_waitcnt vmcnt(" #n ")" ::: "memory")
#define BARR()   asm volatile("s_barrier" ::: "memory")

__global__ __launch_bounds__(512, 2) void gemm256_8ph(
    const unsigned short* __restrict__ A, int lda, long long sA,
    const unsigned short* __restrict__ B, int ldb, long long sB,
    float* __restrict__ Cf, unsigned short* __restrict__ Cb, int ldc,
    long long sC, int K, int mswap)
{
    __shared__ unsigned short sm[65536];   // 128 KB, [buf][A/B][half][128][64]
    A += (long long)blockIdx.z * sA;
    B += (long long)blockIdx.z * sB;
    const int t    = threadIdx.x;
    const int m0   = (mswap ? blockIdx.x : blockIdx.y) * 256;
    const int n0   = (mswap ? blockIdx.y : blockIdx.x) * 256;
    const int lane = t & 63;
    const int w    = t >> 6;
    const int wm   = ((w >> 2) & 1) * 64;   // row base within each A-half
    const int wn   = (w & 3) * 32;          // col base within each B-half
    const int l15  = lane & 15;
    const int l4   = lane >> 4;
    const int NT   = K >> 6;

    const int sr = t >> 3, sl = t & 7;

    auto STAGE = [&](int T, int h, int isB) {
        const unsigned short* G = isB ? B : A;
        const int ld   = isB ? ldb : lda;
        const int base = (isB ? n0 : m0) + h * 128;
        unsigned short* dst =
            &sm[(T & 1) * 32768 + isB * 16384 + h * 8192 + t * 8];
#pragma unroll
        for (int j = 0; j < 2; j++) {
            const int r   = sr + 64 * j;
            const int gch = sl ^ ((r ^ (r >> 3)) & 7);
            gl_lds16(G + (size_t)(base + r) * ld + T * 64 + gch * 8,
                     dst + j * 4096);
        }
    };

    int aoff[4], asw[4], boff[2], bsw[2];
#pragma unroll
    for (int mi = 0; mi < 4; mi++) {
        int r = wm + mi * 16 + l15;
        aoff[mi] = r * 64; asw[mi] = (r ^ (r >> 3)) & 7;
    }
#pragma unroll
    for (int ni = 0; ni < 2; ni++) {
        int r = wn + ni * 16 + l15;
        boff[ni] = r * 64; bsw[ni] = (r ^ (r >> 3)) & 7;
    }

    bf16x8 aF[4][2], bF[2][2][2];
    f32x4  acc[2][2][4][2];
#pragma unroll
    for (int qm = 0; qm < 2; qm++)
#pragma unroll
        for (int qn = 0; qn < 2; qn++)
#pragma unroll
            for (int mi = 0; mi < 4; mi++)
#pragma unroll
                for (int ni = 0; ni < 2; ni++)
                    acc[qm][qn][mi][ni] = (f32x4){0.f, 0.f, 0.f, 0.f};

#define LOAD_A(qm) do { \
    const unsigned short* p_ = &sm[cb + (qm) * 8192]; \
    _Pragma("unroll") for (int mi = 0; mi < 4; mi++) \
    _Pragma("unroll") for (int ks = 0; ks < 2; ks++) \
        aF[mi][ks] = *(const bf16x8*)&p_[aoff[mi] + \
            (((ks * 4 + l4) ^ asw[mi]) << 3)]; \
} while (0)
#define LOAD_B(qn) do { \
    const unsigned short* p_ = &sm[cb + 16384 + (qn) * 8192]; \
    _Pragma("unroll") for (int ni = 0; ni < 2; ni++) \
    _Pragma("unroll") for (int ks = 0; ks < 2; ks++) \
        bF[qn][ni][ks] = *(const bf16x8*)&p_[boff[ni] + \
            (((ks * 4 + l4) ^ bsw[ni]) << 3)]; \
} while (0)
#define MMA(qm, qn) do { \
    __builtin_amdgcn_s_setprio(1); \
    _Pragma("unroll") for (int ks = 0; ks < 2; ks++) \
    _Pragma("unroll") for (int mi = 0; mi < 4; mi++) \
    _Pragma("unroll") for (int ni = 0; ni < 2; ni++) \
        acc[qm][qn][mi][ni] = __builtin_amdgcn_mfma_f32_16x16x32_bf16( \
            aF[mi][ks], bF[qn][ni][ks], acc[qm][qn][mi][ni], 0, 0, 0); \
    __builtin_amdgcn_s_setprio(0); \
} while (0)

    // prologue: stage tile0 + first half-pair of tile1, full drain, barrier.
    STAGE(0, 0, 0);   // A0(0)
    STAGE(0, 1, 1);   // B1(0)
    STAGE(0, 0, 1);   // B0(0)
    STAGE(0, 1, 0);   // A1(0)
    STAGE(1, 0, 0);   // A0(1)
    STAGE(1, 1, 1);   // B1(1)
    WAITV(0);
    BARR();

    for (int tt = 0; tt < NT; tt++) {
        const int cb = (tt & 1) * 32768;
        // ---- phase 0: quadrant (0,0) ----   [A0(tt),B0(tt) drained pre-barrier]
        LOAD_A(0); LOAD_B(0);                        // 12 ds_read_b128
        if (tt + 1 < NT) STAGE(tt + 1, 0, 1);        // B0(t+1)
        BARR();
        MMA(0, 0);
        BARR();
        // ---- phase 1: quadrant (0,1) ----   [B1(tt) drained pre-barrier]
        LOAD_B(1);                                   // 4 ds_read_b128
        if (tt + 1 < NT) STAGE(tt + 1, 1, 0);        // A1(t+1)
        BARR();
        MMA(0, 1);
        if (tt + 1 < NT) { WAITV(8); } else { WAITV(0); }  // drain A1(tt)
        BARR();
        // ---- phase 2: quadrant (1,1) ----
        LOAD_A(1);                                   // 8 ds_read_b128
        if (tt + 2 < NT) STAGE(tt + 2, 0, 0);        // A0(t+2)
        BARR();
        MMA(1, 1);
        BARR();
        // ---- phase 3: quadrant (1,0) ----
        if (tt + 2 < NT) STAGE(tt + 2, 1, 1);        // B1(t+2)
        BARR();
        MMA(1, 0);
        if (tt + 2 < NT)      { WAITV(6); }          // drain A0,B0(tt+1)
        else if (tt + 1 < NT) { WAITV(2); }
        BARR();
    }

#undef LOAD_A
#undef LOAD_B
#undef MMA

    // Epilogue. 16x16 C/D: col = lane&15, row = (lane>>4)*4 + reg
    if (Cb) {
        unsigned short* Cz = Cb + (long long)blockIdx.z * sC;
#pragma unroll
        for (int qm = 0; qm < 2; qm++)
#pragma unroll
        for (int qn = 0; qn < 2; qn++)
#pragma unroll
        for (int mi = 0; mi < 4; mi++)
#pragma unroll
        for (int ni = 0; ni < 2; ni++) {
            const int rb = m0 + qm * 128 + wm + mi * 16 + l4 * 4;
            const int cc = n0 + qn * 128 + wn + ni * 16 + l15;
#pragma unroll
            for (int rr = 0; rr < 4; rr++)
                Cz[(size_t)(rb + rr) * ldc + cc] = f2bf(acc[qm][qn][mi][ni][rr]);
        }
    } else {
        float* Cz = Cf + (long long)blockIdx.z * sC;
#pragma unroll
        for (int qm = 0; qm < 2; qm++)
#pragma unroll
        for (int qn = 0; qn < 2; qn++)
#pragma unroll
        for (int mi = 0; mi < 4; mi++)
#pragma unroll
        for (int ni = 0; ni < 2; ni++) {
            const int rb = m0 + qm * 128 + wm + mi * 16 + l4 * 4;
            const int cc = n0 + qn * 128 + wn + ni * 16 + l15;
#pragma unroll
            for (int rr = 0; rr < 4; rr++)
                Cz[(size_t)(rb + rr) * ldc + cc] = acc[qm][qn][mi][ni][rr];
        }
    }
}

// ---------------------------------------------------------------------------
// bf16 MFMA NT GEMM body (shared by the two occupancy variants below).
// 32x32x16 MFMA, BK=64, XOR bank swizzle. 0 bank conflicts measured.
// ---------------------------------------------------------------------------
__device__ __forceinline__ void gemm_bt_body(
    const unsigned short* __restrict__ A, int lda,
    const unsigned short* __restrict__ B, int ldb,
    float* __restrict__ Cf, unsigned short* __restrict__ Cb, int ldc,
    int K, int m0, int n0,
    unsigned short* As, unsigned short* Bs)
{
    const int t     = threadIdx.x;
    const int w     = t >> 6;
    const int lane  = t & 63;
    const int col   = lane & 31;
    const int khalf = lane >> 5;
    const int wm    = (w & 1) * 64;
    const int wn    = (w >> 1) * 64;

    const int srow  = t >> 3;
    const int sslot = t & 7;
    const unsigned short* Agp[4];
    const unsigned short* Bgp[4];
#pragma unroll
    for (int i = 0; i < 4; i++) {
        const int r   = srow + 32 * i;
        const int gch = sslot ^ ((r ^ (r >> 3)) & 7);
        Agp[i] = A + (size_t)(m0 + r) * lda + gch * 8;
        Bgp[i] = B + (size_t)(n0 + r) * ldb + gch * 8;
    }
    unsigned short* Asl = &As[t * 8];
    unsigned short* Bsl = &Bs[t * 8];

    int aOff[2], aXor[2], bOff[2], bXor[2];
#pragma unroll
    for (int i = 0; i < 2; i++) {
        const int ra = wm + i * 32 + col;
        aOff[i] = ra * 64; aXor[i] = (ra ^ (ra >> 3)) & 7;
        const int rb = wn + i * 32 + col;
        bOff[i] = rb * 64; bXor[i] = (rb ^ (rb >> 3)) & 7;
    }

    f32x16 acc[2][2];
#pragma unroll
    for (int mi = 0; mi < 2; mi++)
#pragma unroll
        for (int ni = 0; ni < 2; ni++)
#pragma unroll
            for (int e = 0; e < 16; e++) acc[mi][ni][e] = 0.f;

    for (int k0 = 0; k0 < K; k0 += 64) {
        __syncthreads();
#pragma unroll
        for (int i = 0; i < 4; i++) {
            gl_lds16(Agp[i] + k0, Asl + i * 2048);
            gl_lds16(Bgp[i] + k0, Bsl + i * 2048);
        }
        __syncthreads();
#pragma unroll
        for (int ks = 0; ks < 4; ks++) {
            const int ch = ks * 2 + khalf;
            bf16x8 af[2], bfr[2];
#pragma unroll
            for (int i = 0; i < 2; i++) {
                af[i]  = *(const bf16x8*)&As[aOff[i] + ((ch ^ aXor[i]) * 8)];
                bfr[i] = *(const bf16x8*)&Bs[bOff[i] + ((ch ^ bXor[i]) * 8)];
            }
#pragma unroll
            for (int mi = 0; mi < 2; mi++)
#pragma unroll
                for (int ni = 0; ni < 2; ni++)
                    acc[mi][ni] = __builtin_amdgcn_mfma_f32_32x32x16_bf16(
                        af[mi], bfr[ni], acc[mi][ni], 0, 0, 0);
        }
    }

    // Epilogue. 32x32 C/D: col = lane&31, row = (reg&3) + 8*(reg>>2) + 4*(lane>>5)
    if (Cb) {
#pragma unroll
        for (int mi = 0; mi < 2; mi++)
#pragma unroll
            for (int ni = 0; ni < 2; ni++) {
                const int rbase = m0 + wm + mi * 32 + 4 * khalf;
                const int cc    = n0 + wn + ni * 32 + col;
#pragma unroll
                for (int g = 0; g < 4; g++)
#pragma unroll
                    for (int rr = 0; rr < 4; rr++)
                        Cb[(size_t)(rbase + 8 * g + rr) * ldc + cc] =
                            f2bf(acc[mi][ni][4 * g + rr]);
            }
    } else {
#pragma unroll
        for (int mi = 0; mi < 2; mi++)
#pragma unroll
            for (int ni = 0; ni < 2; ni++) {
                const int rbase = m0 + wm + mi * 32 + 4 * khalf;
                const int cc    = n0 + wn + ni * 32 + col;
#pragma unroll
                for (int g = 0; g < 4; g++)
#pragma unroll
                    for (int rr = 0; rr < 4; rr++)
                        Cf[(size_t)(rbase + 8 * g + rr) * ldc + cc] =
                            acc[mi][ni][4 * g + rr];
            }
    }
}

// Unconstrained variant (Gm: 32 blocks, occupancy irrelevant).
__global__ __launch_bounds__(256) void gemm_bt_mfma(
    const unsigned short* __restrict__ A, int lda, long long sA,
    const unsigned short* __restrict__ B, int ldb, long long sB,
    float* __restrict__ Cf, unsigned short* __restrict__ Cb, int ldc,
    long long sC, int K, int mswap)
{
    __shared__ unsigned short As[128 * 64];   // 16 KB
    __shared__ unsigned short Bs[128 * 64];   // 16 KB
    A += (long long)blockIdx.z * sA;
    B += (long long)blockIdx.z * sB;
    float* Cz = Cf ? Cf + (long long)blockIdx.z * sC : nullptr;
    const int m0 = (mswap ? blockIdx.x : blockIdx.y) * 128;
    const int n0 = (mswap ? blockIdx.y : blockIdx.x) * 128;
    gemm_bt_body(A, lda, B, ldb, Cz, Cb, ldc, K, m0, n0, As, Bs);
}

// Occupancy-forced variant for GEMM1: __launch_bounds__(256, 4) requests
// 4 waves/EU = 4 blocks/CU (256-thr blocks), capping VGPR at 128/wave
// (64 arch + 64 unified-file accumulator). Theory: reported VGPR=76 arch
// + 64 acc = 140 -> 3 blocks/CU -> 1056-block grid = 1.375 rounds (25%
// tail waste); at 4/CU it's 1.03 rounds. Prediction: GEMM1 96 -> 82-90us;
// unchanged => occupancy wasn't VGPR-limited; regression => spills.
__global__ __launch_bounds__(256, 4) void gemm_bt_mfma4(
    const unsigned short* __restrict__ A, int lda,
    const unsigned short* __restrict__ B, int ldb,
    unsigned short* __restrict__ Cb, int ldc, int K, int mswap)
{
    __shared__ unsigned short As[128 * 64];   // 16 KB
    __shared__ unsigned short Bs[128 * 64];   // 16 KB
    const int m0 = (mswap ? blockIdx.x : blockIdx.y) * 128;
    const int n0 = (mswap ? blockIdx.y : blockIdx.x) * 128;
    gemm_bt_body(A, lda, B, ldb, nullptr, Cb, ldc, K, m0, n0, As, Bs);
}

// ---------------------------------------------------------------------------
// out = p0+p1+p2+p3 (fp32) — split-K=4 reduce for GEMM2
// ---------------------------------------------------------------------------
__global__ __launch_bounds__(256) void addf4_kernel(
    const float* __restrict__ p, float* __restrict__ o)
{
    size_t i = ((size_t)blockIdx.x * 256 + threadIdx.x) * 4;
    float4 a = *(const float4*)(p + i);
    float4 b = *(const float4*)(p + i + 4194304);
    float4 c = *(const float4*)(p + i + 8388608);
    float4 d = *(const float4*)(p + i + 12582912);
    float4 r = make_float4(a.x + b.x + c.x + d.x, a.y + b.y + c.y + d.y,
                           a.z + b.z + c.z + d.z, a.w + b.w + c.w + d.w);
    *(float4*)(o + i) = r;
}

// ---------------------------------------------------------------------------
// fp32 NT GEMM (dt split-K only)
// ---------------------------------------------------------------------------
__global__ __launch_bounds__(256) void gemm_nt(
    const float* __restrict__ A, int lda, long long sA,
    const float* __restrict__ B, int ldb, long long sB,
    float* __restrict__ C, int ldc, long long sC, int K)
{
    A += (long long)blockIdx.z * sA;
    B += (long long)blockIdx.z * sB;
    C += (long long)blockIdx.z * sC;
    const int t  = threadIdx.x;
    const int m0 = blockIdx.y * 128;
    const int n0 = blockIdx.x * 64;
    __shared__ float As[16][132];
    __shared__ float Bs[16][68];
    const int tx = t & 15;
    const int ty = t >> 4;

    const int arow = t & 127;
    const int akh  = (t >> 7) * 8;
    const float* Aload = A + (size_t)(m0 + arow) * (size_t)lda + akh;
    const int brow = t & 63;
    const int bk4  = (t >> 6) * 4;
    const float* Bload = B + (size_t)(n0 + brow) * (size_t)ldb + bk4;

    float acc[8][4];
#pragma unroll
    for (int i = 0; i < 8; i++)
#pragma unroll
        for (int j = 0; j < 4; j++) acc[i][j] = 0.f;

    for (int k0 = 0; k0 < K; k0 += 16) {
        __syncthreads();
        float4 a0 = *(const float4*)(Aload + k0);
        float4 a1 = *(const float4*)(Aload + k0 + 4);
        float4 b0 = *(const float4*)(Bload + k0);
        As[akh + 0][arow] = a0.x; As[akh + 1][arow] = a0.y;
        As[akh + 2][arow] = a0.z; As[akh + 3][arow] = a0.w;
        As[akh + 4][arow] = a1.x; As[akh + 5][arow] = a1.y;
        As[akh + 6][arow] = a1.z; As[akh + 7][arow] = a1.w;
        Bs[bk4 + 0][brow] = b0.x; Bs[bk4 + 1][brow] = b0.y;
        Bs[bk4 + 2][brow] = b0.z; Bs[bk4 + 3][brow] = b0.w;
        __syncthreads();
#pragma unroll
        for (int k = 0; k < 16; k++) {
            float4 a4 = *(const float4*)(&As[k][ty * 8]);
            float4 a5 = *(const float4*)(&As[k][ty * 8 + 4]);
            float4 b4 = *(const float4*)(&Bs[k][tx * 4]);
            float am[8] = {a4.x, a4.y, a4.z, a4.w, a5.x, a5.y, a5.z, a5.w};
            float bn[4] = {b4.x, b4.y, b4.z, b4.w};
#pragma unroll
            for (int i = 0; i < 8; i++)
#pragma unroll
                for (int j = 0; j < 4; j++) acc[i][j] += am[i] * bn[j];
        }
    }
#pragma unroll
    for (int i = 0; i < 8; i++) {
        float4 o = make_float4(acc[i][0], acc[i][1], acc[i][2], acc[i][3]);
        *(float4*)(C + (size_t)(m0 + ty * 8 + i) * (size_t)ldc + n0 + tx * 4) = o;
    }
}

// ---------------------------------------------------------------------------
__global__ __launch_bounds__(256) void dt_reduce_kernel(
    const float* __restrict__ part, const float* __restrict__ dt_bias,
    float* __restrict__ dtg)
{
    const int i = blockIdx.x * 256 + threadIdx.x;
    float x = dt_bias[i & 63];
#pragma unroll
    for (int z = 0; z < 32; z++) x += part[(size_t)z * 131072 + i];
    dtg[i] = (x > 20.f) ? x : log1pf(__expf(x));
}

// ---------------------------------------------------------------------------
// Causal depthwise conv (K=4) + bias + SiLU, 8 outputs/thread along s.
// ---------------------------------------------------------------------------
__global__ __launch_bounds__(256) void conv_silu8_kernel(
    const unsigned short* __restrict__ projbf, const float* __restrict__ conv_w,
    const float* __restrict__ conv_b, unsigned short* __restrict__ out)
{
    const int c  = blockIdx.x * 256 + threadIdx.x;   // [0, 4352)
    const int s0 = blockIdx.y * 8;
    const float4 w = *(const float4*)(conv_w + (size_t)c * 4);
    const float b = conv_b[c];
    const size_t base = 4096 + (size_t)c;
    float v[11];
#pragma unroll
    for (int m = 0; m < 11; m++) {
        int s = s0 - 3 + m;
        v[m] = (s >= 0) ? bf2f(projbf[(size_t)s * GEMM1N + base]) : 0.f;
    }
#pragma unroll
    for (int j = 0; j < 8; j++) {
        float acc = b + v[j] * w.x + v[j + 1] * w.y + v[j + 2] * w.z + v[j + 3] * w.w;
        float sig = 1.f / (1.f + __expf(-acc));
        out[(size_t)(s0 + j) * CONVD + c] = f2bf(acc * sig);
    }
}

// ---------------------------------------------------------------------------
// SSM core, MFMA, bf16 hBC input (unchanged)
// ---------------------------------------------------------------------------
__global__ __launch_bounds__(256, 2) void ssm_mfma_kernel(
    const unsigned short* __restrict__ hBC, const float* __restrict__ dtg,
    const float* __restrict__ Gm, const float* __restrict__ A_log,
    const float* __restrict__ Dp, float* __restrict__ y)
{
    const int h    = blockIdx.x;
    const int c    = blockIdx.y;
    const int t    = threadIdx.x;
    const int wid  = t >> 6;
    const int lane = t & 63;
    const int lo   = lane & 15;
    const int q    = lane >> 4;

    __shared__ float sAcum[CS], sdt[CS], sD[CS], sEs[CS], sDecay[CS], sScl[CS];
    __shared__ float sWaveSum[4];
    __shared__ unsigned short sHdtT[64 * 264];
    __shared__ unsigned short sStT[64 * 136];
    __shared__ unsigned short sBufB[128 * 72];

    const float A = -__expf(A_log[h]);
    const int row0 = c * CS;
    const unsigned short* hid = hBC + (size_t)row0 * CONVD + h * P_DIM;
    const unsigned short* Bp  = hBC + (size_t)row0 * CONVD + INTER;
    const unsigned short* Cp  = hBC + (size_t)row0 * CONVD + INTER + N_DIM;
    const float* gm = Gm + (size_t)c * CS * CS;

    float dtv = dtg[(size_t)(row0 + t) * NH + h];
    float v = A * dtv;
    for (int off = 1; off < 64; off <<= 1) {
        float u = __shfl_up(v, off, 64);
        if (lane >= off) v += u;
    }
    if (lane == 63) sWaveSum[wid] = v;
    __syncthreads();
    float pre = 0.f;
    for (int i = 0; i < 4; i++) if (i < wid) pre += sWaveSum[i];
    v += pre;
    sAcum[t] = v;
    sdt[t] = dtv;
    __syncthreads();
    const float AcumEnd = sAcum[CS - 1];
    {
        float ac   = sAcum[t];
        float apre = (t < 64) ? 0.f : sAcum[(t & ~63) - 1];
        sD[t]     = __expf(ac - apre);
        sEs[t]    = __expf(sAcum[t | 63] - ac);
        sDecay[t] = __expf(AcumEnd - ac);
        sScl[t]   = __expf(ac);
    }

    unsigned short* stgu = sStT;
    for (int lt = 0; lt < 4; lt++) {
        __syncthreads();
        {
            const int c8 = (t & 7) * 8;
#pragma unroll
            for (int j = 0; j < 2; j++) {
                int l = (t >> 3) + 32 * j;
                *(uint4*)&stgu[l * 64 + c8] =
                    *(const uint4*)(hid + (size_t)(lt * 64 + l) * CONVD + c8);
            }
        }
        __syncthreads();
        {
            const int p = t & 63, lq = (t >> 6) * 16;
#pragma unroll
            for (int j = 0; j < 4; j++) {
                ushort4 pk;
                int l0 = lq + j * 4;
                pk.x = f2bf(bf2f(stgu[(l0 + 0) * 64 + p]) * sdt[lt * 64 + l0 + 0]);
                pk.y = f2bf(bf2f(stgu[(l0 + 1) * 64 + p]) * sdt[lt * 64 + l0 + 1]);
                pk.z = f2bf(bf2f(stgu[(l0 + 2) * 64 + p]) * sdt[lt * 64 + l0 + 2]);
                pk.w = f2bf(bf2f(stgu[(l0 + 3) * 64 + p]) * sdt[lt * 64 + l0 + 3]);
                *(uint2*)&sHdtT[p * 264 + lt * 64 + l0] = *(uint2*)&pk;
            }
        }
    }

    f32x4 acc2[2][4];
#pragma unroll
    for (int mi = 0; mi < 2; mi++)
#pragma unroll
        for (int ni = 0; ni < 4; ni++) acc2[mi][ni] = (f32x4){0.f, 0.f, 0.f, 0.f};
    const int psub = (wid & 1) * 32;
    const int nsub = (wid >> 1) * 64;

    for (int qt = 0; qt < 4; qt++) {
        for (int hf = 0; hf < 2; hf++) {
            __syncthreads();
            {
                const int n8 = (t & 15) * 8;
#pragma unroll
                for (int j = 0; j < 2; j++) {
                    int r = (t >> 4) + 16 * j;
                    *(uint4*)&stgu[r * 128 + n8] =
                        *(const uint4*)(Bp + (size_t)(qt * 64 + hf * 32 + r) * CONVD + n8);
                }
            }
            __syncthreads();
            {
                const int n = t & 127, lc = (t >> 7) * 16;
#pragma unroll
                for (int j = 0; j < 4; j++) {
                    int l0 = lc + j * 4;
                    ushort4 pk;
                    pk.x = f2bf(bf2f(stgu[(l0 + 0) * 128 + n]) * sDecay[qt * 64 + hf * 32 + l0 + 0]);
                    pk.y = f2bf(bf2f(stgu[(l0 + 1) * 128 + n]) * sDecay[qt * 64 + hf * 32 + l0 + 1]);
                    pk.z = f2bf(bf2f(stgu[(l0 + 2) * 128 + n]) * sDecay[qt * 64 + hf * 32 + l0 + 2]);
                    pk.w = f2bf(bf2f(stgu[(l0 + 3) * 128 + n]) * sDecay[qt * 64 + hf * 32 + l0 + 3]);
                    *(uint2*)&sBufB[n * 72 + hf * 32 + l0] = *(uint2*)&pk;
                }
            }
        }
        __syncthreads();
#pragma unroll
        for (int ks = 0; ks < 2; ks++) {
            const int k0 = qt * 64 + ks * 32;
            const int kq = ks * 32;
            bf16x8 a2[2], b2[4];
#pragma unroll
            for (int mi = 0; mi < 2; mi++)
                a2[mi] = *(const bf16x8*)&sHdtT[(psub + mi * 16 + lo) * 264 + k0 + q * 8];
#pragma unroll
            for (int ni = 0; ni < 4; ni++)
                b2[ni] = *(const bf16x8*)&sBufB[(nsub + ni * 16 + lo) * 72 + kq + q * 8];
#pragma unroll
            for (int mi = 0; mi < 2; mi++)
#pragma unroll
                for (int ni = 0; ni < 4; ni++)
                    acc2[mi][ni] = __builtin_amdgcn_mfma_f32_16x16x32_bf16(
                        a2[mi], b2[ni], acc2[mi][ni], 0, 0, 0);
        }
    }
    __syncthreads();
#pragma unroll
    for (int mi = 0; mi < 2; mi++)
#pragma unroll
        for (int ni = 0; ni < 4; ni++)
#pragma unroll
            for (int rr = 0; rr < 4; rr++) {
                int p = psub + mi * 16 + q * 4 + rr;
                int n = nsub + ni * 16 + lo;
                sStT[p * 136 + n] = f2bf(acc2[mi][ni][rr]);
            }

    f32x4 accY[4][2][2];
#pragma unroll
    for (int i = 0; i < 4; i++)
#pragma unroll
        for (int mi = 0; mi < 2; mi++)
#pragma unroll
            for (int pi = 0; pi < 2; pi++) accY[i][mi][pi] = (f32x4){0.f, 0.f, 0.f, 0.f};
    const int pcol = (wid & 1) * 32;
    const int rsub = (wid >> 1) * 16;
    unsigned short* Cs = sBufB;

    for (int i = 0; i < 4; i++) {
        __syncthreads();
        {
            const int n8 = (t & 15) * 8;
#pragma unroll
            for (int j = 0; j < 4; j++) {
                int r = (t >> 4) + 16 * j;
                uint4 cv = *(const uint4*)(Cp + (size_t)(i * 64 + r) * CONVD + n8);
                float scl = sScl[i * 64 + r];
                const unsigned short* cu = (const unsigned short*)&cv;
                ushort4 p0, p1;
                p0.x = f2bf(bf2f(cu[0]) * scl); p0.y = f2bf(bf2f(cu[1]) * scl);
                p0.z = f2bf(bf2f(cu[2]) * scl); p0.w = f2bf(bf2f(cu[3]) * scl);
                p1.x = f2bf(bf2f(cu[4]) * scl); p1.y = f2bf(bf2f(cu[5]) * scl);
                p1.z = f2bf(bf2f(cu[6]) * scl); p1.w = f2bf(bf2f(cu[7]) * scl);
                *(uint2*)&Cs[r * 136 + n8]     = *(uint2*)&p0;
                *(uint2*)&Cs[r * 136 + n8 + 4] = *(uint2*)&p1;
            }
        }
        __syncthreads();
#pragma unroll
        for (int ks = 0; ks < 4; ks++) {
            const int k0 = ks * 32;
            bf16x8 a3[2], b3[2];
#pragma unroll
            for (int mi = 0; mi < 2; mi++)
                a3[mi] = *(const bf16x8*)&Cs[(mi * 32 + rsub + lo) * 136 + k0 + q * 8];
#pragma unroll
            for (int pi = 0; pi < 2; pi++)
                b3[pi] = *(const bf16x8*)&sStT[(pcol + pi * 16 + lo) * 136 + k0 + q * 8];
#pragma unroll
            for (int mi = 0; mi < 2; mi++)
#pragma unroll
                for (int pi = 0; pi < 2; pi++)
                    accY[i][mi][pi] = __builtin_amdgcn_mfma_f32_16x16x32_bf16(
                        a3[mi], b3[pi], accY[i][mi][pi], 0, 0, 0);
        }
    }

    unsigned short* Mt = sBufB;
    for (int i = 0; i < 4; i++) {
        const int nk = 2 * (i + 1);
        for (int mi = 0; mi < 2; mi++) {
            __syncthreads();
            if (wid <= i) {
                float P = 1.f;
                for (int m = wid + 1; m <= i - 1; m++) P *= sD[m * 64 + 63];
                const int s4 = wid * 64 + lo * 4;
                float4 es4 = *(const float4*)&sEs[s4];
#pragma unroll
                for (int j = 0; j < 8; j++) {
                    int lr = q + j * 4;
                    int l  = i * 64 + mi * 32 + lr;
                    float4 g4 = *(const float4*)&gm[(size_t)l * CS + s4];
                    float w0, w1, w2, w3;
                    if (wid == i) {
                        float al = sAcum[l];
                        w0 = (s4 + 0 <= l) ? __expf(al - sAcum[s4 + 0]) : 0.f;
                        w1 = (s4 + 1 <= l) ? __expf(al - sAcum[s4 + 1]) : 0.f;
                        w2 = (s4 + 2 <= l) ? __expf(al - sAcum[s4 + 2]) : 0.f;
                        w3 = (s4 + 3 <= l) ? __expf(al - sAcum[s4 + 3]) : 0.f;
                    } else {
                        float rs = sD[l] * P;
                        w0 = rs * es4.x; w1 = rs * es4.y;
                        w2 = rs * es4.z; w3 = rs * es4.w;
                    }
                    ushort4 pk;
                    pk.x = f2bf(g4.x * w0); pk.y = f2bf(g4.y * w1);
                    pk.z = f2bf(g4.z * w2); pk.w = f2bf(g4.w * w3);
                    *(uint2*)&Mt[lr * 264 + s4] = *(uint2*)&pk;
                }
            }
            __syncthreads();
            for (int ks = 0; ks < nk; ks++) {
                const int k0 = ks * 32;
                bf16x8 am = *(const bf16x8*)&Mt[(rsub + lo) * 264 + k0 + q * 8];
                bf16x8 b1[2];
#pragma unroll
                for (int pi = 0; pi < 2; pi++)
                    b1[pi] = *(const bf16x8*)&sHdtT[(pcol + pi * 16 + lo) * 264 + k0 + q * 8];
#pragma unroll
                for (int pi = 0; pi < 2; pi++)
                    accY[i][mi][pi] = __builtin_amdgcn_mfma_f32_16x16x32_bf16(
                        am, b1[pi], accY[i][mi][pi], 0, 0, 0);
            }
        }
    }

    const float Dh = Dp[h];
#pragma unroll
    for (int i = 0; i < 4; i++)
#pragma unroll
        for (int mi = 0; mi < 2; mi++)
#pragma unroll
            for (int pi = 0; pi < 2; pi++)
#pragma unroll
                for (int rr = 0; rr < 4; rr++) {
                    int l = i * 64 + mi * 32 + rsub + q * 4 + rr;
                    int p = pcol + pi * 16 + lo;
                    float hv = bf2f(hid[(size_t)l * CONVD + p]);
                    y[(size_t)(row0 + l) * INTER + h * P_DIM + p] =
                        accY[i][mi][pi][rr] + Dh * hv;
                }
}

// ---------------------------------------------------------------------------
// Gated RMSNorm (unchanged)
// ---------------------------------------------------------------------------
__global__ __launch_bounds__(256) void norm_kernel(
    const float* __restrict__ y, const unsigned short* __restrict__ projbf,
    const float* __restrict__ norm_w, unsigned short* __restrict__ yn)
{
    const int s = blockIdx.x;
    const int t = threadIdx.x;
    __shared__ float sYf[INTER];
    __shared__ float sW[4];
    const float* yrow = y + (size_t)s * INTER;
    const unsigned short* grow = projbf + (size_t)s * GEMM1N;
    float sum = 0.f;
    for (int j0 = 0; j0 < INTER; j0 += 2048) {
        int j = j0 + t * 8;
        float4 y0 = *(const float4*)(yrow + j);
        float4 y1 = *(const float4*)(yrow + j + 4);
        uint4 gp = *(const uint4*)(grow + j);
        float gv[8] = {
            bf2f((unsigned short)(gp.x & 0xffff)), bf2f((unsigned short)(gp.x >> 16)),
            bf2f((unsigned short)(gp.y & 0xffff)), bf2f((unsigned short)(gp.y >> 16)),
            bf2f((unsigned short)(gp.z & 0xffff)), bf2f((unsigned short)(gp.z >> 16)),
            bf2f((unsigned short)(gp.w & 0xffff)), bf2f((unsigned short)(gp.w >> 16))};
        float yv8[8] = {y0.x, y0.y, y0.z, y0.w, y1.x, y1.y, y1.z, y1.w};
#pragma unroll
        for (int e = 0; e < 8; e++) {
            float f = yv8[e] * (gv[e] / (1.f + __expf(-gv[e])));
            sum += f * f;
            sYf[j + e] = f;
        }
    }
    for (int off = 32; off > 0; off >>= 1) sum += __shfl_down(sum, off, 64);
    if ((t & 63) == 0) sW[t >> 6] = sum;
    __syncthreads();
    const float var = (sW[0] + sW[1] + sW[2] + sW[3]) * (1.f / (float)INTER);
    const float rs = rsqrtf(var + EPS);
    for (int j0 = 0; j0 < INTER; j0 += 2048) {
        int j = j0 + t * 8;
        float4 w0 = *(const float4*)(norm_w + j);
        float4 w1 = *(const float4*)(norm_w + j + 4);
        float wv[8] = {w0.x, w0.y, w0.z, w0.w, w1.x, w1.y, w1.z, w1.w};
        unsigned short o[8];
#pragma unroll
        for (int e = 0; e < 8; e++) o[e] = f2bf(sYf[j + e] * wv[e] * rs);
        uint4 ov;
        ov.x = (unsigned int)o[0] | ((unsigned int)o[1] << 16);
        ov.y = (unsigned int)o[2] | ((unsigned int)o[3] << 16);
        ov.z = (unsigned int)o[4] | ((unsigned int)o[5] << 16);
        ov.w = (unsigned int)o[6] | ((unsigned int)o[7] << 16);
        *(uint4*)(yn + (size_t)s * INTER + j) = ov;
    }
}

// ---------------------------------------------------------------------------
extern "C" void kernel_launch(void* const* d_in, const int* in_sizes, int n_in,
                              void* d_out, int out_size, void* d_ws, size_t ws_size,
                              hipStream_t stream)
{
    const float* X       = (const float*)d_in[0];
    const float* W_in    = (const float*)d_in[2];
    const float* conv_w  = (const float*)d_in[3];
    const float* conv_b  = (const float*)d_in[4];
    const float* dt_bias = (const float*)d_in[5];
    const float* A_log   = (const float*)d_in[6];
    const float* Dp      = (const float*)d_in[7];
    const float* norm_w  = (const float*)d_in[8];
    const float* W_out   = (const float*)d_in[9];
    float* out = (float*)d_out;
    float* ws  = (float*)d_ws;

    unsigned short* projbf = (unsigned short*)(ws + OFF_PROJBF);
    unsigned short* hbc16  = (unsigned short*)(ws + OFF_HBC);
    float* dtg     = ws + OFF_DTG;
    float* dtpart  = ws + OFF_DTPART;
    float* gm      = ws + OFF_GM;
    float* yv      = ws + OFF_YV;
    unsigned short* Xbf    = (unsigned short*)(ws + OFF_R);
    unsigned short* Winbf  = (unsigned short*)(ws + OFF_R + 2097152);
    unsigned short* ynbf   = (unsigned short*)(ws + OFF_R);   // aliases Xbf (post-GEMM1)
    unsigned short* Woutbf = (unsigned short*)(ws + OFF_WOUT);
    float* part = ws;   // GEMM2 split-K=4 fp32 partials: ws[0 .. 16,777,216)

    // all three casts in one launch
    cast3_kernel<<<14592, 256, 0, stream>>>(X, W_in, W_out, Xbf, Winbf, Woutbf);

    // GEMM1: 128^2 kernel with forced 4 blocks/CU (occupancy experiment —
    // see gemm_bt_mfma4 comment; single variable vs R8).
    gemm_bt_mfma4<<<dim3(S_LEN / 128, GEMM1N / 128, 1), 256, 0, stream>>>(
        Xbf, E_DIM, Winbf, E_DIM, projbf, GEMM1N, E_DIM, 1);

    // dt columns fp32, split-K=32 (512 blocks)
    gemm_nt<<<dim3(1, 16, 32), 256, 0, stream>>>(
        X, E_DIM, 64LL, W_in + (size_t)GEMM1N * E_DIM, E_DIM, 64LL,
        dtpart, NH, 131072LL, 64);
    dt_reduce_kernel<<<512, 256, 0, stream>>>(dtpart, dt_bias, dtg);

    // conv + silu -> bf16 hBC
    conv_silu8_kernel<<<dim3(CONVD / 256, S_LEN / 8), 256, 0, stream>>>(
        projbf, conv_w, conv_b, hbc16);

    // Gm[c] = Cm_c @ Bm_c^T via bf16 MFMA (fp32 out) — unconstrained variant
    gemm_bt_mfma<<<dim3(CS / 128, CS / 128, NCHUNK), 256, 0, stream>>>(
        hbc16 + INTER + N_DIM, CONVD, (long long)CS * CONVD,
        hbc16 + INTER,         CONVD, (long long)CS * CONVD,
        gm, nullptr, CS, (long long)CS * CS, N_DIM, 0);

    ssm_mfma_kernel<<<dim3(NH, NCHUNK), 256, 0, stream>>>(
        hbc16, dtg, gm, A_log, Dp, yv);

    norm_kernel<<<dim3(S_LEN), 256, 0, stream>>>(yv, projbf, norm_w, ynbf);

    // GEMM2: 256x256 8-phase (race-fixed), split-K=4 -> 256 blocks;
    // fp32 partials.
    gemm256_8ph<<<dim3(E_DIM / 256, S_LEN / 256, 4), 512, 0, stream>>>(
        ynbf, INTER, 1024LL, Woutbf, INTER, 1024LL,
        part, nullptr, E_DIM, 4194304LL, 1024, 0);
    addf4_kernel<<<4096, 256, 0, stream>>>(part, out);
}

// Round 10
// 409.195 us; speedup vs baseline: 1.0204x; 1.0139x over previous
//
#include <hip/hip_runtime.h>
#include <math.h>

// Problem constants
#define S_LEN   2048
#define E_DIM   2048
#define NH      64
#define P_DIM   64
#define N_DIM   128
#define CS      256
#define NCHUNK  8
#define INTER   4096
#define CONVD   4352
#define PROJ    8512
#define GEMM1N  8448       // INTER + CONVD = 66*128 = 33*256 exactly
#define EPS     1e-5f

// Workspace layout (float units)
#define OFF_PROJBF 0ull                        // bf16 2048*8448 = 8,650,752 fl
#define OFF_HBC    8650752ull                  // bf16 2048*4352 = 4,456,448 fl
#define OFF_DTG    13107200ull                 // fp32 2048*64   =   131,072 fl
#define OFF_DTPART 13238272ull                 // fp32 32*2048*64 = 4,194,304 fl
#define OFF_GM     17432576ull                 // fp32 8*256*256 =   524,288 fl
#define OFF_YV     17956864ull                 // fp32 2048*4096 = 8,388,608 fl
#define OFF_R      26345472ull                 // Xbf(2,097,152 fl) + Winbf(8,650,752 fl)
#define OFF_WOUT   37093376ull                 // bf16 2048*4096 = 2,097,152 fl
// ws end = 39,190,528 fl = 156.8 MB.
// ynbf aliases Xbf (R+0) — written by norm, after GEMM1's last read of Xbf.
// GEMM2 split-K=4 partials: 4 x 4,194,304 fl FP32 at ws[0 .. 16,777,216).
//
// SETTLED (measured, R0-R9):
//  - GEMM1 = 128^2 2-phase kernel, natural order, no launch-bounds cap:
//    256^2-8ph loses (2-round 139us / fused-tail 110us vs 96us — 33
//    col-tiles vs 256 CUs is a shape property); XCD swizzle: FETCH -40%
//    but +4% time (latency-bound); forced 4 blocks/CU: spills (+6.4MB
//    writes, +5us). 3 blocks/CU VGPR-optimal.
//  - GEMM2 = 256^2 8-phase race-fixed (wait->barrier->read gates), exactly
//    256 blocks, fp32 split-K=4 partials (bf16 partials: 32B partial-line
//    stores, no gain).

typedef __bf16 bf16x8 __attribute__((ext_vector_type(8)));
typedef float  f32x4  __attribute__((ext_vector_type(4)));
typedef float  f32x16 __attribute__((ext_vector_type(16)));

__device__ __forceinline__ float bf2f(unsigned short u) {
    union { unsigned int i; float f; } v; v.i = ((unsigned int)u) << 16; return v.f;
}
__device__ __forceinline__ unsigned short f2bf(float f) {
    union { float f; unsigned int i; } v; v.f = f;
    unsigned int r = v.i + 0x7FFFu + ((v.i >> 16) & 1u);
    return (unsigned short)(r >> 16);
}
__device__ __forceinline__ void gl_lds16(const void* g, void* l) {
    __builtin_amdgcn_global_load_lds(
        (const __attribute__((address_space(1))) void*)g,
        (__attribute__((address_space(3))) void*)l, 16, 0, 0);
}

// ---------------------------------------------------------------------------
// merged fp32 -> bf16 cast of X / W_in[0:8448] / W_out (one launch)
// ---------------------------------------------------------------------------
__global__ __launch_bounds__(256) void cast3_kernel(
    const float* __restrict__ X, const float* __restrict__ Win,
    const float* __restrict__ Wout, unsigned short* __restrict__ Xbf,
    unsigned short* __restrict__ Winbf, unsigned short* __restrict__ Woutbf)
{
    const int blk = blockIdx.x;
    const float* src; unsigned short* dst; size_t off;
    if (blk < 2048)       { src = X;    dst = Xbf;    off = (size_t)blk * 2048; }
    else if (blk < 10496) { src = Win;  dst = Winbf;  off = (size_t)(blk - 2048) * 2048; }
    else                  { src = Wout; dst = Woutbf; off = (size_t)(blk - 10496) * 2048; }
    size_t i = off + (size_t)threadIdx.x * 8;
    float4 a = *(const float4*)(src + i);
    float4 b = *(const float4*)(src + i + 4);
    uint4 o;
    o.x = (unsigned int)f2bf(a.x) | ((unsigned int)f2bf(a.y) << 16);
    o.y = (unsigned int)f2bf(a.z) | ((unsigned int)f2bf(a.w) << 16);
    o.z = (unsigned int)f2bf(b.x) | ((unsigned int)f2bf(b.y) << 16);
    o.w = (unsigned int)f2bf(b.z) | ((unsigned int)f2bf(b.w) << 16);
    *(uint4*)(dst + i) = o;
}

// ---------------------------------------------------------------------------
// 256x256 8-phase bf16 NT GEMM (HK-style schedule, plain HIP).
// Used ONLY where the grid is exactly <=256 blocks (GEMM2: 8x8x4).
// RACE-FIXED gates (R5/R6, tripwire-verified): vmcnt is PER-WAVE; a
// half-tile is staged by all 8 waves cooperatively, so every gate is
// wait -> BARRIER -> read.
// ---------------------------------------------------------------------------
#define WAITV(n) asm volatile("s_waitcnt vmcnt(" #n ")" ::: "memory")
#define BARR()   asm volatile("s_barrier" ::: "memory")

__global__ __launch_bounds__(512, 2) void gemm256_8ph(
    const unsigned short* __restrict__ A, int lda, long long sA,
    const unsigned short* __restrict__ B, int ldb, long long sB,
    float* __restrict__ Cf, unsigned short* __restrict__ Cb, int ldc,
    long long sC, int K, int mswap)
{
    __shared__ unsigned short sm[65536];   // 128 KB, [buf][A/B][half][128][64]
    A += (long long)blockIdx.z * sA;
    B += (long long)blockIdx.z * sB;
    const int t    = threadIdx.x;
    const int m0   = (mswap ? blockIdx.x : blockIdx.y) * 256;
    const int n0   = (mswap ? blockIdx.y : blockIdx.x) * 256;
    const int lane = t & 63;
    const int w    = t >> 6;
    const int wm   = ((w >> 2) & 1) * 64;   // row base within each A-half
    const int wn   = (w & 3) * 32;          // col base within each B-half
    const int l15  = lane & 15;
    const int l4   = lane >> 4;
    const int NT   = K >> 6;

    const int sr = t >> 3, sl = t & 7;

    auto STAGE = [&](int T, int h, int isB) {
        const unsigned short* G = isB ? B : A;
        const int ld   = isB ? ldb : lda;
        const int base = (isB ? n0 : m0) + h * 128;
        unsigned short* dst =
            &sm[(T & 1) * 32768 + isB * 16384 + h * 8192 + t * 8];
#pragma unroll
        for (int j = 0; j < 2; j++) {
            const int r   = sr + 64 * j;
            const int gch = sl ^ ((r ^ (r >> 3)) & 7);
            gl_lds16(G + (size_t)(base + r) * ld + T * 64 + gch * 8,
                     dst + j * 4096);
        }
    };

    int aoff[4], asw[4], boff[2], bsw[2];
#pragma unroll
    for (int mi = 0; mi < 4; mi++) {
        int r = wm + mi * 16 + l15;
        aoff[mi] = r * 64; asw[mi] = (r ^ (r >> 3)) & 7;
    }
#pragma unroll
    for (int ni = 0; ni < 2; ni++) {
        int r = wn + ni * 16 + l15;
        boff[ni] = r * 64; bsw[ni] = (r ^ (r >> 3)) & 7;
    }

    bf16x8 aF[4][2], bF[2][2][2];
    f32x4  acc[2][2][4][2];
#pragma unroll
    for (int qm = 0; qm < 2; qm++)
#pragma unroll
        for (int qn = 0; qn < 2; qn++)
#pragma unroll
            for (int mi = 0; mi < 4; mi++)
#pragma unroll
                for (int ni = 0; ni < 2; ni++)
                    acc[qm][qn][mi][ni] = (f32x4){0.f, 0.f, 0.f, 0.f};

#define LOAD_A(qm) do { \
    const unsigned short* p_ = &sm[cb + (qm) * 8192]; \
    _Pragma("unroll") for (int mi = 0; mi < 4; mi++) \
    _Pragma("unroll") for (int ks = 0; ks < 2; ks++) \
        aF[mi][ks] = *(const bf16x8*)&p_[aoff[mi] + \
            (((ks * 4 + l4) ^ asw[mi]) << 3)]; \
} while (0)
#define LOAD_B(qn) do { \
    const unsigned short* p_ = &sm[cb + 16384 + (qn) * 8192]; \
    _Pragma("unroll") for (int ni = 0; ni < 2; ni++) \
    _Pragma("unroll") for (int ks = 0; ks < 2; ks++) \
        bF[qn][ni][ks] = *(const bf16x8*)&p_[boff[ni] + \
            (((ks * 4 + l4) ^ bsw[ni]) << 3)]; \
} while (0)
#define MMA(qm, qn) do { \
    __builtin_amdgcn_s_setprio(1); \
    _Pragma("unroll") for (int ks = 0; ks < 2; ks++) \
    _Pragma("unroll") for (int mi = 0; mi < 4; mi++) \
    _Pragma("unroll") for (int ni = 0; ni < 2; ni++) \
        acc[qm][qn][mi][ni] = __builtin_amdgcn_mfma_f32_16x16x32_bf16( \
            aF[mi][ks], bF[qn][ni][ks], acc[qm][qn][mi][ni], 0, 0, 0); \
    __builtin_amdgcn_s_setprio(0); \
} while (0)

    // prologue: stage tile0 + first half-pair of tile1, full drain, barrier.
    STAGE(0, 0, 0);   // A0(0)
    STAGE(0, 1, 1);   // B1(0)
    STAGE(0, 0, 1);   // B0(0)
    STAGE(0, 1, 0);   // A1(0)
    STAGE(1, 0, 0);   // A0(1)
    STAGE(1, 1, 1);   // B1(1)
    WAITV(0);
    BARR();

    for (int tt = 0; tt < NT; tt++) {
        const int cb = (tt & 1) * 32768;
        // ---- phase 0: quadrant (0,0) ----   [A0(tt),B0(tt) drained pre-barrier]
        LOAD_A(0); LOAD_B(0);                        // 12 ds_read_b128
        if (tt + 1 < NT) STAGE(tt + 1, 0, 1);        // B0(t+1)
        BARR();
        MMA(0, 0);
        BARR();
        // ---- phase 1: quadrant (0,1) ----   [B1(tt) drained pre-barrier]
        LOAD_B(1);                                   // 4 ds_read_b128
        if (tt + 1 < NT) STAGE(tt + 1, 1, 0);        // A1(t+1)
        BARR();
        MMA(0, 1);
        if (tt + 1 < NT) { WAITV(8); } else { WAITV(0); }  // drain A1(tt)
        BARR();
        // ---- phase 2: quadrant (1,1) ----
        LOAD_A(1);                                   // 8 ds_read_b128
        if (tt + 2 < NT) STAGE(tt + 2, 0, 0);        // A0(t+2)
        BARR();
        MMA(1, 1);
        BARR();
        // ---- phase 3: quadrant (1,0) ----
        if (tt + 2 < NT) STAGE(tt + 2, 1, 1);        // B1(t+2)
        BARR();
        MMA(1, 0);
        if (tt + 2 < NT)      { WAITV(6); }          // drain A0,B0(tt+1)
        else if (tt + 1 < NT) { WAITV(2); }
        BARR();
    }

#undef LOAD_A
#undef LOAD_B
#undef MMA

    // Epilogue. 16x16 C/D: col = lane&15, row = (lane>>4)*4 + reg
    if (Cb) {
        unsigned short* Cz = Cb + (long long)blockIdx.z * sC;
#pragma unroll
        for (int qm = 0; qm < 2; qm++)
#pragma unroll
        for (int qn = 0; qn < 2; qn++)
#pragma unroll
        for (int mi = 0; mi < 4; mi++)
#pragma unroll
        for (int ni = 0; ni < 2; ni++) {
            const int rb = m0 + qm * 128 + wm + mi * 16 + l4 * 4;
            const int cc = n0 + qn * 128 + wn + ni * 16 + l15;
#pragma unroll
            for (int rr = 0; rr < 4; rr++)
                Cz[(size_t)(rb + rr) * ldc + cc] = f2bf(acc[qm][qn][mi][ni][rr]);
        }
    } else {
        float* Cz = Cf + (long long)blockIdx.z * sC;
#pragma unroll
        for (int qm = 0; qm < 2; qm++)
#pragma unroll
        for (int qn = 0; qn < 2; qn++)
#pragma unroll
        for (int mi = 0; mi < 4; mi++)
#pragma unroll
        for (int ni = 0; ni < 2; ni++) {
            const int rb = m0 + qm * 128 + wm + mi * 16 + l4 * 4;
            const int cc = n0 + qn * 128 + wn + ni * 16 + l15;
#pragma unroll
            for (int rr = 0; rr < 4; rr++)
                Cz[(size_t)(rb + rr) * ldc + cc] = acc[qm][qn][mi][ni][rr];
        }
    }
}

// ---------------------------------------------------------------------------
// bf16 MFMA NT GEMM, 32x32x16 MFMA, BK=64, XOR bank swizzle.
// 0 bank conflicts, 3 blocks/CU (VGPR-optimal: forcing 4/CU spills, R9).
// Used for GEMM1 (1056 blocks) and Gm (32 blocks).
// ---------------------------------------------------------------------------
__global__ __launch_bounds__(256) void gemm_bt_mfma(
    const unsigned short* __restrict__ A, int lda, long long sA,
    const unsigned short* __restrict__ B, int ldb, long long sB,
    float* __restrict__ Cf, unsigned short* __restrict__ Cb, int ldc,
    long long sC, int K, int mswap)
{
    __shared__ unsigned short As[128 * 64];   // 16 KB
    __shared__ unsigned short Bs[128 * 64];   // 16 KB
    A += (long long)blockIdx.z * sA;
    B += (long long)blockIdx.z * sB;
    const int t     = threadIdx.x;
    const int m0    = (mswap ? blockIdx.x : blockIdx.y) * 128;
    const int n0    = (mswap ? blockIdx.y : blockIdx.x) * 128;
    const int w     = t >> 6;
    const int lane  = t & 63;
    const int col   = lane & 31;
    const int khalf = lane >> 5;
    const int wm    = (w & 1) * 64;
    const int wn    = (w >> 1) * 64;

    const int srow  = t >> 3;
    const int sslot = t & 7;
    const unsigned short* Agp[4];
    const unsigned short* Bgp[4];
#pragma unroll
    for (int i = 0; i < 4; i++) {
        const int r   = srow + 32 * i;
        const int gch = sslot ^ ((r ^ (r >> 3)) & 7);
        Agp[i] = A + (size_t)(m0 + r) * lda + gch * 8;
        Bgp[i] = B + (size_t)(n0 + r) * ldb + gch * 8;
    }
    unsigned short* Asl = &As[t * 8];
    unsigned short* Bsl = &Bs[t * 8];

    int aOff[2], aXor[2], bOff[2], bXor[2];
#pragma unroll
    for (int i = 0; i < 2; i++) {
        const int ra = wm + i * 32 + col;
        aOff[i] = ra * 64; aXor[i] = (ra ^ (ra >> 3)) & 7;
        const int rb = wn + i * 32 + col;
        bOff[i] = rb * 64; bXor[i] = (rb ^ (rb >> 3)) & 7;
    }

    f32x16 acc[2][2];
#pragma unroll
    for (int mi = 0; mi < 2; mi++)
#pragma unroll
        for (int ni = 0; ni < 2; ni++)
#pragma unroll
            for (int e = 0; e < 16; e++) acc[mi][ni][e] = 0.f;

    for (int k0 = 0; k0 < K; k0 += 64) {
        __syncthreads();
#pragma unroll
        for (int i = 0; i < 4; i++) {
            gl_lds16(Agp[i] + k0, Asl + i * 2048);
            gl_lds16(Bgp[i] + k0, Bsl + i * 2048);
        }
        __syncthreads();
#pragma unroll
        for (int ks = 0; ks < 4; ks++) {
            const int ch = ks * 2 + khalf;
            bf16x8 af[2], bfr[2];
#pragma unroll
            for (int i = 0; i < 2; i++) {
                af[i]  = *(const bf16x8*)&As[aOff[i] + ((ch ^ aXor[i]) * 8)];
                bfr[i] = *(const bf16x8*)&Bs[bOff[i] + ((ch ^ bXor[i]) * 8)];
            }
#pragma unroll
            for (int mi = 0; mi < 2; mi++)
#pragma unroll
                for (int ni = 0; ni < 2; ni++)
                    acc[mi][ni] = __builtin_amdgcn_mfma_f32_32x32x16_bf16(
                        af[mi], bfr[ni], acc[mi][ni], 0, 0, 0);
        }
    }

    // Epilogue. 32x32 C/D: col = lane&31, row = (reg&3) + 8*(reg>>2) + 4*(lane>>5)
    if (Cb) {
#pragma unroll
        for (int mi = 0; mi < 2; mi++)
#pragma unroll
            for (int ni = 0; ni < 2; ni++) {
                const int rbase = m0 + wm + mi * 32 + 4 * khalf;
                const int cc    = n0 + wn + ni * 32 + col;
#pragma unroll
                for (int g = 0; g < 4; g++)
#pragma unroll
                    for (int rr = 0; rr < 4; rr++)
                        Cb[(size_t)(rbase + 8 * g + rr) * ldc + cc] =
                            f2bf(acc[mi][ni][4 * g + rr]);
            }
    } else {
        float* Cz = Cf + (long long)blockIdx.z * sC;
#pragma unroll
        for (int mi = 0; mi < 2; mi++)
#pragma unroll
            for (int ni = 0; ni < 2; ni++) {
                const int rbase = m0 + wm + mi * 32 + 4 * khalf;
                const int cc    = n0 + wn + ni * 32 + col;
#pragma unroll
                for (int g = 0; g < 4; g++)
#pragma unroll
                    for (int rr = 0; rr < 4; rr++)
                        Cz[(size_t)(rbase + 8 * g + rr) * ldc + cc] =
                            acc[mi][ni][4 * g + rr];
            }
    }
}

// ---------------------------------------------------------------------------
// out = p0+p1+p2+p3 (fp32) — split-K=4 reduce for GEMM2
// ---------------------------------------------------------------------------
__global__ __launch_bounds__(256) void addf4_kernel(
    const float* __restrict__ p, float* __restrict__ o)
{
    size_t i = ((size_t)blockIdx.x * 256 + threadIdx.x) * 4;
    float4 a = *(const float4*)(p + i);
    float4 b = *(const float4*)(p + i + 4194304);
    float4 c = *(const float4*)(p + i + 8388608);
    float4 d = *(const float4*)(p + i + 12582912);
    float4 r = make_float4(a.x + b.x + c.x + d.x, a.y + b.y + c.y + d.y,
                           a.z + b.z + c.z + d.z, a.w + b.w + c.w + d.w);
    *(float4*)(o + i) = r;
}

// ---------------------------------------------------------------------------
// fp32 NT GEMM (dt split-K only)
// ---------------------------------------------------------------------------
__global__ __launch_bounds__(256) void gemm_nt(
    const float* __restrict__ A, int lda, long long sA,
    const float* __restrict__ B, int ldb, long long sB,
    float* __restrict__ C, int ldc, long long sC, int K)
{
    A += (long long)blockIdx.z * sA;
    B += (long long)blockIdx.z * sB;
    C += (long long)blockIdx.z * sC;
    const int t  = threadIdx.x;
    const int m0 = blockIdx.y * 128;
    const int n0 = blockIdx.x * 64;
    __shared__ float As[16][132];
    __shared__ float Bs[16][68];
    const int tx = t & 15;
    const int ty = t >> 4;

    const int arow = t & 127;
    const int akh  = (t >> 7) * 8;
    const float* Aload = A + (size_t)(m0 + arow) * (size_t)lda + akh;
    const int brow = t & 63;
    const int bk4  = (t >> 6) * 4;
    const float* Bload = B + (size_t)(n0 + brow) * (size_t)ldb + bk4;

    float acc[8][4];
#pragma unroll
    for (int i = 0; i < 8; i++)
#pragma unroll
        for (int j = 0; j < 4; j++) acc[i][j] = 0.f;

    for (int k0 = 0; k0 < K; k0 += 16) {
        __syncthreads();
        float4 a0 = *(const float4*)(Aload + k0);
        float4 a1 = *(const float4*)(Aload + k0 + 4);
        float4 b0 = *(const float4*)(Bload + k0);
        As[akh + 0][arow] = a0.x; As[akh + 1][arow] = a0.y;
        As[akh + 2][arow] = a0.z; As[akh + 3][arow] = a0.w;
        As[akh + 4][arow] = a1.x; As[akh + 5][arow] = a1.y;
        As[akh + 6][arow] = a1.z; As[akh + 7][arow] = a1.w;
        Bs[bk4 + 0][brow] = b0.x; Bs[bk4 + 1][brow] = b0.y;
        Bs[bk4 + 2][brow] = b0.z; Bs[bk4 + 3][brow] = b0.w;
        __syncthreads();
#pragma unroll
        for (int k = 0; k < 16; k++) {
            float4 a4 = *(const float4*)(&As[k][ty * 8]);
            float4 a5 = *(const float4*)(&As[k][ty * 8 + 4]);
            float4 b4 = *(const float4*)(&Bs[k][tx * 4]);
            float am[8] = {a4.x, a4.y, a4.z, a4.w, a5.x, a5.y, a5.z, a5.w};
            float bn[4] = {b4.x, b4.y, b4.z, b4.w};
#pragma unroll
            for (int i = 0; i < 8; i++)
#pragma unroll
                for (int j = 0; j < 4; j++) acc[i][j] += am[i] * bn[j];
        }
    }
#pragma unroll
    for (int i = 0; i < 8; i++) {
        float4 o = make_float4(acc[i][0], acc[i][1], acc[i][2], acc[i][3]);
        *(float4*)(C + (size_t)(m0 + ty * 8 + i) * (size_t)ldc + n0 + tx * 4) = o;
    }
}

// ---------------------------------------------------------------------------
__global__ __launch_bounds__(256) void dt_reduce_kernel(
    const float* __restrict__ part, const float* __restrict__ dt_bias,
    float* __restrict__ dtg)
{
    const int i = blockIdx.x * 256 + threadIdx.x;
    float x = dt_bias[i & 63];
#pragma unroll
    for (int z = 0; z < 32; z++) x += part[(size_t)z * 131072 + i];
    dtg[i] = (x > 20.f) ? x : log1pf(__expf(x));
}

// ---------------------------------------------------------------------------
// Causal depthwise conv (K=4) + bias + SiLU, 8 outputs/thread along s.
// ---------------------------------------------------------------------------
__global__ __launch_bounds__(256) void conv_silu8_kernel(
    const unsigned short* __restrict__ projbf, const float* __restrict__ conv_w,
    const float* __restrict__ conv_b, unsigned short* __restrict__ out)
{
    const int c  = blockIdx.x * 256 + threadIdx.x;   // [0, 4352)
    const int s0 = blockIdx.y * 8;
    const float4 w = *(const float4*)(conv_w + (size_t)c * 4);
    const float b = conv_b[c];
    const size_t base = 4096 + (size_t)c;
    float v[11];
#pragma unroll
    for (int m = 0; m < 11; m++) {
        int s = s0 - 3 + m;
        v[m] = (s >= 0) ? bf2f(projbf[(size_t)s * GEMM1N + base]) : 0.f;
    }
#pragma unroll
    for (int j = 0; j < 8; j++) {
        float acc = b + v[j] * w.x + v[j + 1] * w.y + v[j + 2] * w.z + v[j + 3] * w.w;
        float sig = 1.f / (1.f + __expf(-acc));
        out[(size_t)(s0 + j) * CONVD + c] = f2bf(acc * sig);
    }
}

// ---------------------------------------------------------------------------
// SSM core, MFMA, bf16 hBC input (unchanged)
// ---------------------------------------------------------------------------
__global__ __launch_bounds__(256, 2) void ssm_mfma_kernel(
    const unsigned short* __restrict__ hBC, const float* __restrict__ dtg,
    const float* __restrict__ Gm, const float* __restrict__ A_log,
    const float* __restrict__ Dp, float* __restrict__ y)
{
    const int h    = blockIdx.x;
    const int c    = blockIdx.y;
    const int t    = threadIdx.x;
    const int wid  = t >> 6;
    const int lane = t & 63;
    const int lo   = lane & 15;
    const int q    = lane >> 4;

    __shared__ float sAcum[CS], sdt[CS], sD[CS], sEs[CS], sDecay[CS], sScl[CS];
    __shared__ float sWaveSum[4];
    __shared__ unsigned short sHdtT[64 * 264];
    __shared__ unsigned short sStT[64 * 136];
    __shared__ unsigned short sBufB[128 * 72];

    const float A = -__expf(A_log[h]);
    const int row0 = c * CS;
    const unsigned short* hid = hBC + (size_t)row0 * CONVD + h * P_DIM;
    const unsigned short* Bp  = hBC + (size_t)row0 * CONVD + INTER;
    const unsigned short* Cp  = hBC + (size_t)row0 * CONVD + INTER + N_DIM;
    const float* gm = Gm + (size_t)c * CS * CS;

    float dtv = dtg[(size_t)(row0 + t) * NH + h];
    float v = A * dtv;
    for (int off = 1; off < 64; off <<= 1) {
        float u = __shfl_up(v, off, 64);
        if (lane >= off) v += u;
    }
    if (lane == 63) sWaveSum[wid] = v;
    __syncthreads();
    float pre = 0.f;
    for (int i = 0; i < 4; i++) if (i < wid) pre += sWaveSum[i];
    v += pre;
    sAcum[t] = v;
    sdt[t] = dtv;
    __syncthreads();
    const float AcumEnd = sAcum[CS - 1];
    {
        float ac   = sAcum[t];
        float apre = (t < 64) ? 0.f : sAcum[(t & ~63) - 1];
        sD[t]     = __expf(ac - apre);
        sEs[t]    = __expf(sAcum[t | 63] - ac);
        sDecay[t] = __expf(AcumEnd - ac);
        sScl[t]   = __expf(ac);
    }

    unsigned short* stgu = sStT;
    for (int lt = 0; lt < 4; lt++) {
        __syncthreads();
        {
            const int c8 = (t & 7) * 8;
#pragma unroll
            for (int j = 0; j < 2; j++) {
                int l = (t >> 3) + 32 * j;
                *(uint4*)&stgu[l * 64 + c8] =
                    *(const uint4*)(hid + (size_t)(lt * 64 + l) * CONVD + c8);
            }
        }
        __syncthreads();
        {
            const int p = t & 63, lq = (t >> 6) * 16;
#pragma unroll
            for (int j = 0; j < 4; j++) {
                ushort4 pk;
                int l0 = lq + j * 4;
                pk.x = f2bf(bf2f(stgu[(l0 + 0) * 64 + p]) * sdt[lt * 64 + l0 + 0]);
                pk.y = f2bf(bf2f(stgu[(l0 + 1) * 64 + p]) * sdt[lt * 64 + l0 + 1]);
                pk.z = f2bf(bf2f(stgu[(l0 + 2) * 64 + p]) * sdt[lt * 64 + l0 + 2]);
                pk.w = f2bf(bf2f(stgu[(l0 + 3) * 64 + p]) * sdt[lt * 64 + l0 + 3]);
                *(uint2*)&sHdtT[p * 264 + lt * 64 + l0] = *(uint2*)&pk;
            }
        }
    }

    f32x4 acc2[2][4];
#pragma unroll
    for (int mi = 0; mi < 2; mi++)
#pragma unroll
        for (int ni = 0; ni < 4; ni++) acc2[mi][ni] = (f32x4){0.f, 0.f, 0.f, 0.f};
    const int psub = (wid & 1) * 32;
    const int nsub = (wid >> 1) * 64;

    for (int qt = 0; qt < 4; qt++) {
        for (int hf = 0; hf < 2; hf++) {
            __syncthreads();
            {
                const int n8 = (t & 15) * 8;
#pragma unroll
                for (int j = 0; j < 2; j++) {
                    int r = (t >> 4) + 16 * j;
                    *(uint4*)&stgu[r * 128 + n8] =
                        *(const uint4*)(Bp + (size_t)(qt * 64 + hf * 32 + r) * CONVD + n8);
                }
            }
            __syncthreads();
            {
                const int n = t & 127, lc = (t >> 7) * 16;
#pragma unroll
                for (int j = 0; j < 4; j++) {
                    int l0 = lc + j * 4;
                    ushort4 pk;
                    pk.x = f2bf(bf2f(stgu[(l0 + 0) * 128 + n]) * sDecay[qt * 64 + hf * 32 + l0 + 0]);
                    pk.y = f2bf(bf2f(stgu[(l0 + 1) * 128 + n]) * sDecay[qt * 64 + hf * 32 + l0 + 1]);
                    pk.z = f2bf(bf2f(stgu[(l0 + 2) * 128 + n]) * sDecay[qt * 64 + hf * 32 + l0 + 2]);
                    pk.w = f2bf(bf2f(stgu[(l0 + 3) * 128 + n]) * sDecay[qt * 64 + hf * 32 + l0 + 3]);
                    *(uint2*)&sBufB[n * 72 + hf * 32 + l0] = *(uint2*)&pk;
                }
            }
        }
        __syncthreads();
#pragma unroll
        for (int ks = 0; ks < 2; ks++) {
            const int k0 = qt * 64 + ks * 32;
            const int kq = ks * 32;
            bf16x8 a2[2], b2[4];
#pragma unroll
            for (int mi = 0; mi < 2; mi++)
                a2[mi] = *(const bf16x8*)&sHdtT[(psub + mi * 16 + lo) * 264 + k0 + q * 8];
#pragma unroll
            for (int ni = 0; ni < 4; ni++)
                b2[ni] = *(const bf16x8*)&sBufB[(nsub + ni * 16 + lo) * 72 + kq + q * 8];
#pragma unroll
            for (int mi = 0; mi < 2; mi++)
#pragma unroll
                for (int ni = 0; ni < 4; ni++)
                    acc2[mi][ni] = __builtin_amdgcn_mfma_f32_16x16x32_bf16(
                        a2[mi], b2[ni], acc2[mi][ni], 0, 0, 0);
        }
    }
    __syncthreads();
#pragma unroll
    for (int mi = 0; mi < 2; mi++)
#pragma unroll
        for (int ni = 0; ni < 4; ni++)
#pragma unroll
            for (int rr = 0; rr < 4; rr++) {
                int p = psub + mi * 16 + q * 4 + rr;
                int n = nsub + ni * 16 + lo;
                sStT[p * 136 + n] = f2bf(acc2[mi][ni][rr]);
            }

    f32x4 accY[4][2][2];
#pragma unroll
    for (int i = 0; i < 4; i++)
#pragma unroll
        for (int mi = 0; mi < 2; mi++)
#pragma unroll
            for (int pi = 0; pi < 2; pi++) accY[i][mi][pi] = (f32x4){0.f, 0.f, 0.f, 0.f};
    const int pcol = (wid & 1) * 32;
    const int rsub = (wid >> 1) * 16;
    unsigned short* Cs = sBufB;

    for (int i = 0; i < 4; i++) {
        __syncthreads();
        {
            const int n8 = (t & 15) * 8;
#pragma unroll
            for (int j = 0; j < 4; j++) {
                int r = (t >> 4) + 16 * j;
                uint4 cv = *(const uint4*)(Cp + (size_t)(i * 64 + r) * CONVD + n8);
                float scl = sScl[i * 64 + r];
                const unsigned short* cu = (const unsigned short*)&cv;
                ushort4 p0, p1;
                p0.x = f2bf(bf2f(cu[0]) * scl); p0.y = f2bf(bf2f(cu[1]) * scl);
                p0.z = f2bf(bf2f(cu[2]) * scl); p0.w = f2bf(bf2f(cu[3]) * scl);
                p1.x = f2bf(bf2f(cu[4]) * scl); p1.y = f2bf(bf2f(cu[5]) * scl);
                p1.z = f2bf(bf2f(cu[6]) * scl); p1.w = f2bf(bf2f(cu[7]) * scl);
                *(uint2*)&Cs[r * 136 + n8]     = *(uint2*)&p0;
                *(uint2*)&Cs[r * 136 + n8 + 4] = *(uint2*)&p1;
            }
        }
        __syncthreads();
#pragma unroll
        for (int ks = 0; ks < 4; ks++) {
            const int k0 = ks * 32;
            bf16x8 a3[2], b3[2];
#pragma unroll
            for (int mi = 0; mi < 2; mi++)
                a3[mi] = *(const bf16x8*)&Cs[(mi * 32 + rsub + lo) * 136 + k0 + q * 8];
#pragma unroll
            for (int pi = 0; pi < 2; pi++)
                b3[pi] = *(const bf16x8*)&sStT[(pcol + pi * 16 + lo) * 136 + k0 + q * 8];
#pragma unroll
            for (int mi = 0; mi < 2; mi++)
#pragma unroll
                for (int pi = 0; pi < 2; pi++)
                    accY[i][mi][pi] = __builtin_amdgcn_mfma_f32_16x16x32_bf16(
                        a3[mi], b3[pi], accY[i][mi][pi], 0, 0, 0);
        }
    }

    unsigned short* Mt = sBufB;
    for (int i = 0; i < 4; i++) {
        const int nk = 2 * (i + 1);
        for (int mi = 0; mi < 2; mi++) {
            __syncthreads();
            if (wid <= i) {
                float P = 1.f;
                for (int m = wid + 1; m <= i - 1; m++) P *= sD[m * 64 + 63];
                const int s4 = wid * 64 + lo * 4;
                float4 es4 = *(const float4*)&sEs[s4];
#pragma unroll
                for (int j = 0; j < 8; j++) {
                    int lr = q + j * 4;
                    int l  = i * 64 + mi * 32 + lr;
                    float4 g4 = *(const float4*)&gm[(size_t)l * CS + s4];
                    float w0, w1, w2, w3;
                    if (wid == i) {
                        float al = sAcum[l];
                        w0 = (s4 + 0 <= l) ? __expf(al - sAcum[s4 + 0]) : 0.f;
                        w1 = (s4 + 1 <= l) ? __expf(al - sAcum[s4 + 1]) : 0.f;
                        w2 = (s4 + 2 <= l) ? __expf(al - sAcum[s4 + 2]) : 0.f;
                        w3 = (s4 + 3 <= l) ? __expf(al - sAcum[s4 + 3]) : 0.f;
                    } else {
                        float rs = sD[l] * P;
                        w0 = rs * es4.x; w1 = rs * es4.y;
                        w2 = rs * es4.z; w3 = rs * es4.w;
                    }
                    ushort4 pk;
                    pk.x = f2bf(g4.x * w0); pk.y = f2bf(g4.y * w1);
                    pk.z = f2bf(g4.z * w2); pk.w = f2bf(g4.w * w3);
                    *(uint2*)&Mt[lr * 264 + s4] = *(uint2*)&pk;
                }
            }
            __syncthreads();
            for (int ks = 0; ks < nk; ks++) {
                const int k0 = ks * 32;
                bf16x8 am = *(const bf16x8*)&Mt[(rsub + lo) * 264 + k0 + q * 8];
                bf16x8 b1[2];
#pragma unroll
                for (int pi = 0; pi < 2; pi++)
                    b1[pi] = *(const bf16x8*)&sHdtT[(pcol + pi * 16 + lo) * 264 + k0 + q * 8];
#pragma unroll
                for (int pi = 0; pi < 2; pi++)
                    accY[i][mi][pi] = __builtin_amdgcn_mfma_f32_16x16x32_bf16(
                        am, b1[pi], accY[i][mi][pi], 0, 0, 0);
            }
        }
    }

    const float Dh = Dp[h];
#pragma unroll
    for (int i = 0; i < 4; i++)
#pragma unroll
        for (int mi = 0; mi < 2; mi++)
#pragma unroll
            for (int pi = 0; pi < 2; pi++)
#pragma unroll
                for (int rr = 0; rr < 4; rr++) {
                    int l = i * 64 + mi * 32 + rsub + q * 4 + rr;
                    int p = pcol + pi * 16 + lo;
                    float hv = bf2f(hid[(size_t)l * CONVD + p]);
                    y[(size_t)(row0 + l) * INTER + h * P_DIM + p] =
                        accY[i][mi][pi][rr] + Dh * hv;
                }
}

// ---------------------------------------------------------------------------
// Gated RMSNorm (unchanged)
// ---------------------------------------------------------------------------
__global__ __launch_bounds__(256) void norm_kernel(
    const float* __restrict__ y, const unsigned short* __restrict__ projbf,
    const float* __restrict__ norm_w, unsigned short* __restrict__ yn)
{
    const int s = blockIdx.x;
    const int t = threadIdx.x;
    __shared__ float sYf[INTER];
    __shared__ float sW[4];
    const float* yrow = y + (size_t)s * INTER;
    const unsigned short* grow = projbf + (size_t)s * GEMM1N;
    float sum = 0.f;
    for (int j0 = 0; j0 < INTER; j0 += 2048) {
        int j = j0 + t * 8;
        float4 y0 = *(const float4*)(yrow + j);
        float4 y1 = *(const float4*)(yrow + j + 4);
        uint4 gp = *(const uint4*)(grow + j);
        float gv[8] = {
            bf2f((unsigned short)(gp.x & 0xffff)), bf2f((unsigned short)(gp.x >> 16)),
            bf2f((unsigned short)(gp.y & 0xffff)), bf2f((unsigned short)(gp.y >> 16)),
            bf2f((unsigned short)(gp.z & 0xffff)), bf2f((unsigned short)(gp.z >> 16)),
            bf2f((unsigned short)(gp.w & 0xffff)), bf2f((unsigned short)(gp.w >> 16))};
        float yv8[8] = {y0.x, y0.y, y0.z, y0.w, y1.x, y1.y, y1.z, y1.w};
#pragma unroll
        for (int e = 0; e < 8; e++) {
            float f = yv8[e] * (gv[e] / (1.f + __expf(-gv[e])));
            sum += f * f;
            sYf[j + e] = f;
        }
    }
    for (int off = 32; off > 0; off >>= 1) sum += __shfl_down(sum, off, 64);
    if ((t & 63) == 0) sW[t >> 6] = sum;
    __syncthreads();
    const float var = (sW[0] + sW[1] + sW[2] + sW[3]) * (1.f / (float)INTER);
    const float rs = rsqrtf(var + EPS);
    for (int j0 = 0; j0 < INTER; j0 += 2048) {
        int j = j0 + t * 8;
        float4 w0 = *(const float4*)(norm_w + j);
        float4 w1 = *(const float4*)(norm_w + j + 4);
        float wv[8] = {w0.x, w0.y, w0.z, w0.w, w1.x, w1.y, w1.z, w1.w};
        unsigned short o[8];
#pragma unroll
        for (int e = 0; e < 8; e++) o[e] = f2bf(sYf[j + e] * wv[e] * rs);
        uint4 ov;
        ov.x = (unsigned int)o[0] | ((unsigned int)o[1] << 16);
        ov.y = (unsigned int)o[2] | ((unsigned int)o[3] << 16);
        ov.z = (unsigned int)o[4] | ((unsigned int)o[5] << 16);
        ov.w = (unsigned int)o[6] | ((unsigned int)o[7] << 16);
        *(uint4*)(yn + (size_t)s * INTER + j) = ov;
    }
}

// ---------------------------------------------------------------------------
extern "C" void kernel_launch(void* const* d_in, const int* in_sizes, int n_in,
                              void* d_out, int out_size, void* d_ws, size_t ws_size,
                              hipStream_t stream)
{
    const float* X       = (const float*)d_in[0];
    const float* W_in    = (const float*)d_in[2];
    const float* conv_w  = (const float*)d_in[3];
    const float* conv_b  = (const float*)d_in[4];
    const float* dt_bias = (const float*)d_in[5];
    const float* A_log   = (const float*)d_in[6];
    const float* Dp      = (const float*)d_in[7];
    const float* norm_w  = (const float*)d_in[8];
    const float* W_out   = (const float*)d_in[9];
    float* out = (float*)d_out;
    float* ws  = (float*)d_ws;

    unsigned short* projbf = (unsigned short*)(ws + OFF_PROJBF);
    unsigned short* hbc16  = (unsigned short*)(ws + OFF_HBC);
    float* dtg     = ws + OFF_DTG;
    float* dtpart  = ws + OFF_DTPART;
    float* gm      = ws + OFF_GM;
    float* yv      = ws + OFF_YV;
    unsigned short* Xbf    = (unsigned short*)(ws + OFF_R);
    unsigned short* Winbf  = (unsigned short*)(ws + OFF_R + 2097152);
    unsigned short* ynbf   = (unsigned short*)(ws + OFF_R);   // aliases Xbf (post-GEMM1)
    unsigned short* Woutbf = (unsigned short*)(ws + OFF_WOUT);
    float* part = ws;   // GEMM2 split-K=4 fp32 partials: ws[0 .. 16,777,216)

    // all three casts in one launch
    cast3_kernel<<<14592, 256, 0, stream>>>(X, W_in, W_out, Xbf, Winbf, Woutbf);

    // GEMM1: 128^2 kernel, natural order, no occupancy cap (R9: forcing
    // 4 blocks/CU spills — 3/CU is VGPR-optimal)
    gemm_bt_mfma<<<dim3(S_LEN / 128, GEMM1N / 128, 1), 256, 0, stream>>>(
        Xbf, E_DIM, 0LL, Winbf, E_DIM, 0LL, nullptr, projbf, GEMM1N, 0LL,
        E_DIM, 1);

    // dt columns fp32, split-K=32 (512 blocks)
    gemm_nt<<<dim3(1, 16, 32), 256, 0, stream>>>(
        X, E_DIM, 64LL, W_in + (size_t)GEMM1N * E_DIM, E_DIM, 64LL,
        dtpart, NH, 131072LL, 64);
    dt_reduce_kernel<<<512, 256, 0, stream>>>(dtpart, dt_bias, dtg);

    // conv + silu -> bf16 hBC
    conv_silu8_kernel<<<dim3(CONVD / 256, S_LEN / 8), 256, 0, stream>>>(
        projbf, conv_w, conv_b, hbc16);

    // Gm[c] = Cm_c @ Bm_c^T via bf16 MFMA (fp32 out)
    gemm_bt_mfma<<<dim3(CS / 128, CS / 128, NCHUNK), 256, 0, stream>>>(
        hbc16 + INTER + N_DIM, CONVD, (long long)CS * CONVD,
        hbc16 + INTER,         CONVD, (long long)CS * CONVD,
        gm, nullptr, CS, (long long)CS * CS, N_DIM, 0);

    ssm_mfma_kernel<<<dim3(NH, NCHUNK), 256, 0, stream>>>(
        hbc16, dtg, gm, A_log, Dp, yv);

    norm_kernel<<<dim3(S_LEN), 256, 0, stream>>>(yv, projbf, norm_w, ynbf);

    // GEMM2: 256x256 8-phase (race-fixed), split-K=4 -> 256 blocks;
    // fp32 partials.
    gemm256_8ph<<<dim3(E_DIM / 256, S_LEN / 256, 4), 512, 0, stream>>>(
        ynbf, INTER, 1024LL, Woutbf, INTER, 1024LL,
        part, nullptr, E_DIM, 4194304LL, 1024, 0);
    addf4_kernel<<<4096, 256, 0, stream>>>(part, out);
}